// Round 2
// baseline (7907.175 us; speedup 1.0000x reference)
//
#include <hip/hip_runtime.h>
#include <cmath>

// ============================================================================
// VAEEncoder on MI355X — round 2
//  * all activations bf16 in workspace (halves footprint + traffic)
//  * Y aliases hs region (safe by chunk ordering)
//  * ws_size-adaptive batch chunking NC in {1024..32}
//  * every matmul through bf16-MFMA gemm_b<TRANSB,EPI,OUTF32>
// ============================================================================

typedef __attribute__((ext_vector_type(8))) short bf16x8;
typedef __attribute__((ext_vector_type(4))) short s16x4;
typedef __attribute__((ext_vector_type(4))) float f32x4;

#define DEVINL __device__ __forceinline__

DEVINL short f2bf(float f) {
  union { float f; unsigned u; } v; v.f = f;
  unsigned r = v.u + 0x7fffu + ((v.u >> 16) & 1u);   // RNE
  return (short)(r >> 16);
}
DEVINL float bf2f(short s) {
  union { unsigned u; float f; } v; v.u = ((unsigned)(unsigned short)s) << 16; return v.f;
}
DEVINL float wred_sum(float v) {
  #pragma unroll
  for (int o = 32; o; o >>= 1) v += __shfl_xor(v, o);
  return v;
}
DEVINL float wred_max(float v) {
  #pragma unroll
  for (int o = 32; o; o >>= 1) v = fmaxf(v, __shfl_xor(v, o));
  return v;
}
DEVINL float geluf(float x) { return 0.5f * x * (1.f + erff(x * 0.7071067811865475f)); }

// ---------------------------------------------------------------------------
// weight f32 -> bf16 copy
// ---------------------------------------------------------------------------
__global__ __launch_bounds__(256) void wcvt(const float* __restrict__ src, short* __restrict__ dst, int n)
{
  int i = blockIdx.x * 256 + threadIdx.x;
  if (i < n) dst[i] = f2bf(src[i]);
}

// ---------------------------------------------------------------------------
// pre1: te/ce/re = gelu(LN(row)) for 32+13+13 table rows (f32, tiny)
// ---------------------------------------------------------------------------
__global__ __launch_bounds__(64) void pre_emb(
    const float* __restrict__ emb_tile, const float* __restrict__ ltg, const float* __restrict__ ltb,
    const float* __restrict__ emb_col,  const float* __restrict__ lcg, const float* __restrict__ lcb,
    const float* __restrict__ emb_row,  const float* __restrict__ lrg, const float* __restrict__ lrb,
    float* __restrict__ te, float* __restrict__ ce, float* __restrict__ re)
{
  int r = blockIdx.x, l = threadIdx.x;
  const float *src, *g, *b; float* dst;
  if (r < 32)      { src = emb_tile + r * 128;       g = ltg; b = ltb; dst = te + r * 128; }
  else if (r < 45) { src = emb_col + (r - 32) * 128; g = lcg; b = lcb; dst = ce + (r - 32) * 128; }
  else             { src = emb_row + (r - 45) * 128; g = lrg; b = lrb; dst = re + (r - 45) * 128; }
  float v0 = src[l], v1 = src[64 + l];
  float m = wred_sum(v0 + v1) * (1.f / 128.f);
  float d0 = v0 - m, d1 = v1 - m;
  float var = wred_sum(d0 * d0 + d1 * d1) * (1.f / 128.f);
  float rstd = rsqrtf(var + 1e-5f);
  dst[l]      = geluf(d0 * rstd * g[l]      + b[l]);
  dst[64 + l] = geluf(d1 * rstd * g[64 + l] + b[64 + l]);
}

// ---------------------------------------------------------------------------
// pre2: tf[v][d] = te[v].efus_W[d,0:128] ; pf[s][d] = ce.W[d,128:256]+re.W[d,256:384]+eb[d]
// ---------------------------------------------------------------------------
__global__ __launch_bounds__(256) void pre_fuse(
    const float* __restrict__ te, const float* __restrict__ ce, const float* __restrict__ re,
    const float* __restrict__ W, const float* __restrict__ eb,
    float* __restrict__ tf, float* __restrict__ pf)
{
  __shared__ float buf[256];
  int r = blockIdx.x, t = threadIdx.x;
  if (r < 32) {
    if (t < 128) buf[t] = te[r * 128 + t];
    __syncthreads();
    float a = 0.f;
    for (int j = 0; j < 128; j++) a += buf[j] * W[t * 384 + j];
    tf[r * 256 + t] = a;
  } else {
    int s = r - 32, col = s % 13, row = s / 13;
    if (t < 128) buf[t] = ce[col * 128 + t];
    else         buf[t] = re[row * 128 + (t - 128)];
    __syncthreads();
    float a = eb[t];
    for (int j = 0; j < 128; j++) a += buf[j] * W[t * 384 + 128 + j];
    for (int j = 0; j < 128; j++) a += buf[128 + j] * W[t * 384 + 256 + j];
    pf[s * 256 + t] = a;
  }
}

// ---------------------------------------------------------------------------
// pre3: tgi[v][g] = tf[v].Wi[g,:] ; pgi[s][g] = pf[s].Wi[g,:] + bi[g]
// ---------------------------------------------------------------------------
__global__ __launch_bounds__(256) void pre_gi(
    const float* __restrict__ tf, const float* __restrict__ pf,
    const float* __restrict__ Wi, const float* __restrict__ bi,
    float* __restrict__ tgi, float* __restrict__ pgi)
{
  __shared__ float buf[256];
  int r = blockIdx.x, t = threadIdx.x;
  const float* src = (r < 32) ? tf + r * 256 : pf + (r - 32) * 256;
  buf[t] = src[t];
  __syncthreads();
  for (int gb = 0; gb < 1536; gb += 256) {
    int g = gb + t;
    float a = 0.f;
    for (int d = 0; d < 256; d++) a += buf[d] * Wi[(long)g * 256 + d];
    if (r < 32) tgi[r * 1536 + g] = a;
    else        pgi[(r - 32) * 1536 + g] = a + bi[g];
  }
}

// ---------------------------------------------------------------------------
// pre4: pack Wh [1536,512] f32 -> bf16 MFMA B-fragments
// ---------------------------------------------------------------------------
__global__ __launch_bounds__(64) void pre_whpack(const float* __restrict__ Wh, short* __restrict__ whpk)
{
  int kt = blockIdx.x / 96, ti = blockIdx.x % 96;
  int l = threadIdx.x;
  int gcol = ti * 16 + (l & 15);
  int kb = kt * 32 + (l >> 4) * 8;
  short* dst = whpk + ((long)(kt * 96 + ti) * 64 + l) * 8;
  #pragma unroll
  for (int j = 0; j < 8; j++) dst[j] = f2bf(Wh[(long)gcol * 512 + kb + j]);
}

// ---------------------------------------------------------------------------
// GRU scan: 64 blocks x 16 batches, 512 thr. h f32 master in LDS, bf16 shadow
// (XOR-swizzled) feeds MFMA A. hs output bf16.
// ---------------------------------------------------------------------------
__global__ __launch_bounds__(512) void gru_scan(
    const int* __restrict__ x, const float* __restrict__ tgi, const float* __restrict__ pgi,
    const short* __restrict__ whpk, const float* __restrict__ bh, short* __restrict__ hs)
{
  __shared__ float h[16][520];
  __shared__ short hbf[16 * 512];   // (r,k) at r*512 + (k ^ ((r&7)<<3))
  __shared__ float bh_l[1536];
  int tid = threadIdx.x, w = tid >> 6, l = tid & 63;
  int lr = l & 15, lg = l >> 4;
  int b0 = blockIdx.x * 16;

  for (int i = tid; i < 16 * 520; i += 512) (&h[0][0])[i] = 0.f;
  for (int i = tid; i < 16 * 512; i += 512) hbf[i] = 0;
  for (int i = tid; i < 1536; i += 512) bh_l[i] = bh[i];
  __syncthreads();

  for (int s = 0; s < 169; s++) {
    int xv[4];
    #pragma unroll
    for (int i = 0; i < 4; i++) xv[i] = x[(b0 + lg * 4 + i) * 169 + s];
    float gi[12][4];
    #pragma unroll
    for (int j = 0; j < 12; j++) {
      int q = j >> 2, t = j & 3;
      int g = q * 512 + w * 64 + t * 16 + lr;
      float pg = pgi[s * 1536 + g];
      #pragma unroll
      for (int i = 0; i < 4; i++) gi[j][i] = tgi[xv[i] * 1536 + g] + pg;
    }
    f32x4 acc[12];
    #pragma unroll
    for (int j = 0; j < 12; j++) acc[j] = (f32x4){0.f, 0.f, 0.f, 0.f};
    #pragma unroll 2
    for (int kt = 0; kt < 16; kt++) {
      int ke = kt * 32 + lg * 8;
      bf16x8 af = *(const bf16x8*)&hbf[lr * 512 + (ke ^ ((lr & 7) << 3))];
      #pragma unroll
      for (int j = 0; j < 12; j++) {
        int q = j >> 2, t = j & 3;
        int ti = q * 32 + w * 4 + t;
        bf16x8 bfr = *(const bf16x8*)&whpk[((long)(kt * 96 + ti) * 64 + l) * 8];
        acc[j] = __builtin_amdgcn_mfma_f32_16x16x32_bf16(af, bfr, acc[j], 0, 0, 0);
      }
    }
    __syncthreads();
    #pragma unroll
    for (int t = 0; t < 4; t++) {
      int k = w * 64 + t * 16 + lr;
      float bhr = bh_l[k], bhz = bh_l[512 + k], bhn = bh_l[1024 + k];
      #pragma unroll
      for (int i = 0; i < 4; i++) {
        int row = lg * 4 + i;
        float r = 1.f / (1.f + expf(-(gi[0 * 4 + t][i] + acc[0 * 4 + t][i] + bhr)));
        float z = 1.f / (1.f + expf(-(gi[1 * 4 + t][i] + acc[1 * 4 + t][i] + bhz)));
        float n = tanhf(gi[2 * 4 + t][i] + r * (acc[2 * 4 + t][i] + bhn));
        float ho = h[row][k];
        float hn2 = (1.f - z) * n + z * ho;
        h[row][k] = hn2;
        short hv = f2bf(hn2);
        hbf[row * 512 + (k ^ ((row & 7) << 3))] = hv;
        hs[((long)(b0 + row) * 169 + s) * 512 + k] = hv;
      }
    }
    __syncthreads();
  }
}

// ---------------------------------------------------------------------------
// bf16 GEMM staging helpers
// ---------------------------------------------------------------------------
DEVINL void stage_rm_bf(const short* __restrict__ src, int ld, int nrows, int K, int k0,
                        short* lds, int tid, int vec)
{
  int sr = tid >> 1, seg = (tid & 1) * 32;
  const short* p = src + (long)sr * ld + k0 + seg;
  bool rowok = sr < nrows;
  #pragma unroll
  for (int i = 0; i < 4; i++) {
    int kg = k0 + seg + 8 * i;
    bf16x8 v;
    if (rowok && vec && (kg + 7 < K)) {
      v = *(const bf16x8*)(p + 8 * i);
    } else {
      #pragma unroll
      for (int j = 0; j < 8; j++) v[j] = (rowok && kg + j < K) ? p[8 * i + j] : (short)0;
    }
    int kl = seg + 8 * i;
    *(bf16x8*)&lds[sr * 64 + (kl ^ ((sr & 7) << 3))] = v;
  }
}

DEVINL void stage_tp_bf(const short* __restrict__ src, int ld, int K, int k0,
                        int ncols, short* lds, int tid)
{
  int kk = tid >> 2, cb = (tid & 3) * 32;
  const short* p = src + (long)(k0 + kk) * ld + cb;
  bool kok = (k0 + kk) < K;
  #pragma unroll
  for (int i = 0; i < 4; i++) {
    int c0 = cb + 8 * i;
    bf16x8 v;
    if (kok && ((ld & 7) == 0) && (c0 + 7 < ncols)) {
      v = *(const bf16x8*)(p + 8 * i);
    } else {
      #pragma unroll
      for (int j = 0; j < 8; j++) v[j] = (kok && c0 + j < ncols) ? p[8 * i + j] : (short)0;
    }
    #pragma unroll
    for (int j = 0; j < 8; j++) {
      int n = c0 + j;
      lds[n * 64 + (kk ^ ((n & 7) << 3))] = v[j];
    }
  }
}

// ---------------------------------------------------------------------------
// bf16 GEMM: C[M,N] = A[M,K] @ op(B) (+bias)(+relu). A,B bf16; C f32 or bf16.
// TRANSB: B is [N,K]; else B is [K,N]. 128x128 tile, BK=64, 4 waves.
// ---------------------------------------------------------------------------
template <bool TRANSB, int EPI, bool OUTF32>
__global__ __launch_bounds__(256) void gemm_b(
    const short* __restrict__ A, int lda, long sA,
    const short* __restrict__ Bm, int ldb, long sB,
    const float* __restrict__ bias,
    void* __restrict__ Cv, int ldc, long sC,
    int M, int N, int K, int ntiles, int vecA)
{
  __shared__ short a_lds[128 * 64];
  __shared__ short b_lds[128 * 64];
  const short* Ab = A + (long)blockIdx.y * sA;
  const short* Bb = Bm + (long)blockIdx.y * sB;
  int mt = blockIdx.x / ntiles, nt = blockIdx.x % ntiles;
  int m0 = mt * 128, n0 = nt * 128;
  int tid = threadIdx.x, w = tid >> 6, l = tid & 63;
  int wm = (w >> 1) * 64, wn = (w & 1) * 64;
  int lr = l & 15, lg = l >> 4;
  int nrA = M - m0; if (nrA > 128) nrA = 128;
  int nrB = N - n0; if (nrB > 128) nrB = 128;

  f32x4 acc[4][4];
  #pragma unroll
  for (int a = 0; a < 4; a++)
    #pragma unroll
    for (int b = 0; b < 4; b++) acc[a][b] = (f32x4){0.f, 0.f, 0.f, 0.f};

  for (int k0 = 0; k0 < K; k0 += 64) {
    __syncthreads();
    stage_rm_bf(Ab + (long)m0 * lda, lda, nrA, K, k0, a_lds, tid, vecA);
    if (TRANSB) stage_rm_bf(Bb + (long)n0 * ldb, ldb, nrB, K, k0, b_lds, tid, 1);
    else        stage_tp_bf(Bb + n0, ldb, K, k0, nrB, b_lds, tid);
    __syncthreads();
    #pragma unroll
    for (int kt = 0; kt < 2; kt++) {
      int ke = kt * 32 + lg * 8;
      bf16x8 af[4], bfr[4];
      #pragma unroll
      for (int mi = 0; mi < 4; mi++) {
        int row = wm + mi * 16 + lr;
        af[mi] = *(const bf16x8*)&a_lds[row * 64 + (ke ^ ((row & 7) << 3))];
      }
      #pragma unroll
      for (int ni = 0; ni < 4; ni++) {
        int col = wn + ni * 16 + lr;
        bfr[ni] = *(const bf16x8*)&b_lds[col * 64 + (ke ^ ((col & 7) << 3))];
      }
      #pragma unroll
      for (int mi = 0; mi < 4; mi++)
        #pragma unroll
        for (int ni = 0; ni < 4; ni++)
          acc[mi][ni] = __builtin_amdgcn_mfma_f32_16x16x32_bf16(af[mi], bfr[ni], acc[mi][ni], 0, 0, 0);
    }
  }
  #pragma unroll
  for (int mi = 0; mi < 4; mi++) {
    #pragma unroll
    for (int ni = 0; ni < 4; ni++) {
      #pragma unroll
      for (int i = 0; i < 4; i++) {
        int row = m0 + wm + mi * 16 + lg * 4 + i;
        int col = n0 + wn + ni * 16 + lr;
        if (row < M && col < N) {
          float v = acc[mi][ni][i];
          if (EPI >= 1) v += bias[col];
          if (EPI == 2) v = fmaxf(v, 0.f);
          long idx = (long)blockIdx.y * sC + (long)row * ldc + col;
          if (OUTF32) ((float*)Cv)[idx] = v;
          else        ((short*)Cv)[idx] = f2bf(v);
        }
      }
    }
  }
}

// ---------------------------------------------------------------------------
// elementwise / reduction (bf16 activations)
// ---------------------------------------------------------------------------
__global__ __launch_bounds__(256) void ln_gelu_512b(
    short* __restrict__ U, const float* __restrict__ g, const float* __restrict__ b, int nrows)
{
  int row = blockIdx.x * 4 + (threadIdx.x >> 6);
  if (row >= nrows) return;
  int l = threadIdx.x & 63;
  short* p = U + (long)row * 512;
  bf16x8 v = *(bf16x8*)(p + l * 8);
  float f[8];
  #pragma unroll
  for (int j = 0; j < 8; j++) f[j] = bf2f(v[j]);
  float s = 0.f;
  #pragma unroll
  for (int j = 0; j < 8; j++) s += f[j];
  float m = wred_sum(s) * (1.f / 512.f);
  float sq = 0.f;
  #pragma unroll
  for (int j = 0; j < 8; j++) { f[j] -= m; sq += f[j] * f[j]; }
  float rstd = rsqrtf(wred_sum(sq) * (1.f / 512.f) + 1e-5f);
  bf16x8 o;
  #pragma unroll
  for (int j = 0; j < 8; j++) {
    float gv = g[l * 8 + j], bv = b[l * 8 + j];
    o[j] = f2bf(geluf(f[j] * rstd * gv + bv));
  }
  *(bf16x8*)(p + l * 8) = o;
}

__global__ __launch_bounds__(256) void res_lnb(
    short* __restrict__ y, const short* __restrict__ o,
    const float* __restrict__ g, const float* __restrict__ b)
{
  long row = (long)blockIdx.x * 4 + (threadIdx.x >> 6);
  int l = threadIdx.x & 63;
  short* p = y + row * 256;
  const short* q = o + row * 256;
  s16x4 yv = *(s16x4*)(p + l * 4);
  s16x4 ov = *(const s16x4*)(q + l * 4);
  float t[4];
  #pragma unroll
  for (int j = 0; j < 4; j++) t[j] = bf2f(yv[j]) + bf2f(ov[j]);
  float m = wred_sum(t[0] + t[1] + t[2] + t[3]) * (1.f / 256.f);
  float sq = 0.f;
  #pragma unroll
  for (int j = 0; j < 4; j++) { t[j] -= m; sq += t[j] * t[j]; }
  float rstd = rsqrtf(wred_sum(sq) * (1.f / 256.f) + 1e-5f);
  s16x4 w;
  #pragma unroll
  for (int j = 0; j < 4; j++) w[j] = f2bf(t[j] * rstd * g[l * 4 + j] + b[l * 4 + j]);
  *(s16x4*)(p + l * 4) = w;
}

__global__ __launch_bounds__(256) void softmax_169b(short* __restrict__ sc)
{
  long row = (long)blockIdx.x * 4 + (threadIdx.x >> 6);
  int l = threadIdx.x & 63;
  short* p = sc + row * 169;
  const float scale = 0.08838834764831845f;   // 1/sqrt(128)
  float v[3]; float mx = -3.4e38f;
  #pragma unroll
  for (int j = 0; j < 3; j++) {
    int c = l + 64 * j;
    v[j] = (c < 169) ? bf2f(p[c]) * scale : -3.4e38f;
    mx = fmaxf(mx, v[j]);
  }
  mx = wred_max(mx);
  float sum = 0.f;
  #pragma unroll
  for (int j = 0; j < 3; j++) {
    int c = l + 64 * j;
    v[j] = (c < 169) ? expf(v[j] - mx) : 0.f;
    sum += v[j];
  }
  sum = wred_sum(sum);
  float inv = 1.f / sum;
  #pragma unroll
  for (int j = 0; j < 3; j++) { int c = l + 64 * j; if (c < 169) p[c] = f2bf(v[j] * inv); }
}

// final LN + mean/max pooling -> hp[b][0:256]=mean, [256:512]=max (bf16)
__global__ __launch_bounds__(256) void final_poolb(
    const short* __restrict__ y, const float* __restrict__ g, const float* __restrict__ b,
    short* __restrict__ hp)
{
  __shared__ float sm[4][256], sx[4][256];
  int bb = blockIdx.x;
  int w = threadIdx.x >> 6, l = threadIdx.x & 63;
  float am[4] = {0.f, 0.f, 0.f, 0.f};
  float ax[4] = {-3.4e38f, -3.4e38f, -3.4e38f, -3.4e38f};
  float gl[4], bl[4];
  #pragma unroll
  for (int j = 0; j < 4; j++) { gl[j] = g[l * 4 + j]; bl[j] = b[l * 4 + j]; }
  for (int s = w; s < 169; s += 4) {
    s16x4 vv = *(const s16x4*)(y + ((long)bb * 169 + s) * 256 + l * 4);
    float t[4];
    #pragma unroll
    for (int j = 0; j < 4; j++) t[j] = bf2f(vv[j]);
    float m = wred_sum(t[0] + t[1] + t[2] + t[3]) * (1.f / 256.f);
    float sq = 0.f;
    #pragma unroll
    for (int j = 0; j < 4; j++) { t[j] -= m; sq += t[j] * t[j]; }
    float rstd = rsqrtf(wred_sum(sq) * (1.f / 256.f) + 1e-5f);
    #pragma unroll
    for (int j = 0; j < 4; j++) {
      float o = t[j] * rstd * gl[j] + bl[j];
      am[j] += o; ax[j] = fmaxf(ax[j], o);
    }
  }
  #pragma unroll
  for (int j = 0; j < 4; j++) { sm[w][l * 4 + j] = am[j]; sx[w][l * 4 + j] = ax[j]; }
  __syncthreads();
  if (w == 0) {
    #pragma unroll
    for (int j = 0; j < 4; j++) {
      int c = l * 4 + j;
      float ms = sm[0][c] + sm[1][c] + sm[2][c] + sm[3][c];
      float mx = fmaxf(fmaxf(sx[0][c], sx[1][c]), fmaxf(sx[2][c], sx[3][c]));
      hp[(long)bb * 512 + c] = f2bf(ms * (1.f / 169.f));
      hp[(long)bb * 512 + 256 + c] = f2bf(mx);
    }
  }
}

// ---------------------------------------------------------------------------
// host
// ---------------------------------------------------------------------------
static void launch_gemm(hipStream_t st, bool transb, int epi, bool outf32,
                        const short* A, int lda, long sA,
                        const short* B, int ldb, long sB,
                        const float* bias, void* C, int ldc, long sC,
                        int M, int N, int K, int nb, int vecA)
{
  int mt = (M + 127) >> 7, nt = (N + 127) >> 7;
  dim3 grid(mt * nt, nb), blk(256);
#define GO(TB, EP, OF) gemm_b<TB, EP, OF><<<grid, blk, 0, st>>>(A, lda, sA, B, ldb, sB, bias, C, ldc, sC, M, N, K, nt, vecA)
  if (transb) {
    if (outf32)      GO(true, 1, true);
    else if (epi == 0) GO(true, 0, false);
    else if (epi == 1) GO(true, 1, false);
    else               GO(true, 2, false);
  } else {
    GO(false, 0, false);
  }
#undef GO
}

extern "C" void kernel_launch(void* const* d_in, const int* in_sizes, int n_in,
                              void* d_out, int out_size, void* d_ws, size_t ws_size,
                              hipStream_t stream)
{
  const int*   x        = (const int*)d_in[0];
  const float* emb_tile = (const float*)d_in[1];
  const float* ln_t_g   = (const float*)d_in[2];
  const float* ln_t_b   = (const float*)d_in[3];
  const float* emb_col  = (const float*)d_in[4];
  const float* ln_c_g   = (const float*)d_in[5];
  const float* ln_c_b   = (const float*)d_in[6];
  const float* emb_row  = (const float*)d_in[7];
  const float* ln_r_g   = (const float*)d_in[8];
  const float* ln_r_b   = (const float*)d_in[9];
  const float* efus_W   = (const float*)d_in[10];
  const float* efus_b   = (const float*)d_in[11];
  const float* gru_Wi   = (const float*)d_in[12];
  const float* gru_Wh   = (const float*)d_in[13];
  const float* gru_bi   = (const float*)d_in[14];
  const float* gru_bh   = (const float*)d_in[15];
  const float* rfc1_W   = (const float*)d_in[16];
  const float* rfc1_b   = (const float*)d_in[17];
  const float* rln_g    = (const float*)d_in[18];
  const float* rln_b    = (const float*)d_in[19];
  const float* rfc2_W   = (const float*)d_in[20];
  const float* rfc2_b   = (const float*)d_in[21];
  const float* t_inW    = (const float*)d_in[22];
  const float* t_inb    = (const float*)d_in[23];
  const float* t_outW   = (const float*)d_in[24];
  const float* t_outb   = (const float*)d_in[25];
  const float* t_ln1g   = (const float*)d_in[26];
  const float* t_ln1b   = (const float*)d_in[27];
  const float* t_ff1W   = (const float*)d_in[28];
  const float* t_ff1b   = (const float*)d_in[29];
  const float* t_ff2W   = (const float*)d_in[30];
  const float* t_ff2b   = (const float*)d_in[31];
  const float* t_ln2g   = (const float*)d_in[32];
  const float* t_ln2b   = (const float*)d_in[33];
  const float* fnorm_g  = (const float*)d_in[34];
  const float* fnorm_b  = (const float*)d_in[35];
  const float* ffc_W    = (const float*)d_in[36];
  const float* ffc_b    = (const float*)d_in[37];
  const float* ffc_lng  = (const float*)d_in[38];
  const float* ffc_lnb  = (const float*)d_in[39];
  const float* mu_W     = (const float*)d_in[40];
  const float* mu_b     = (const float*)d_in[41];
  const float* lv_W     = (const float*)d_in[42];
  const float* lv_b     = (const float*)d_in[43];
  float* out = (float*)d_out;

  char* ws = (char*)d_ws;

  // ---- small region (8 MB) ----
  float* te   = (float*)(ws + 0);
  float* ce   = (float*)(ws + 16384);
  float* re   = (float*)(ws + 23040);
  float* tf   = (float*)(ws + 29696);
  float* pf   = (float*)(ws + 62464);
  float* tgi  = (float*)(ws + 235520);
  float* pgi  = (float*)(ws + 432128);
  short* whpk = (short*)(ws + 1470464);
  short* wp   = (short*)(ws + 3043328);   // 1474560 bf16 weights
  short* hp   = (short*)(ws + 5992448);   // [1024,512] bf16
  short* h2   = (short*)(ws + 7041024);   // [1024,512] bf16

  short* rfc1p = wp;
  short* rfc2p = wp + 262144;
  short* inWp  = wp + 393216;   // 2 x 768 x 256
  short* outWp = wp + 786432;   // 2 x 256 x 256
  short* ff1p  = wp + 917504;
  short* ff2p  = wp + 1048576;
  short* ffcp  = wp + 1179648;
  short* mup   = wp + 1441792;
  short* lvp   = wp + 1458176;

  // ---- big regions: hs [BS,512] bf16; Y aliases hs base (safe by chunk order) ----
  const size_t o_hs = 8388608;
  short* hs = (short*)(ws + o_hs);        // 177,209,344 B
  short* Y  = hs;                          // [BS,256] bf16 overlay
  const size_t o_R = o_hs + 177209344ULL; // scratch region

  // ---- adaptive batch chunk ----
  size_t Ravail = ws_size > o_R ? ws_size - o_R : 0;
  int NC = 1024;
  while (NC > 32 && (size_t)NC * 360192ULL > Ravail) NC >>= 1;
  char* R = ws + o_R;
  short* Uc  = (short*)R;                                  // [NC*169,512]
  short* qb  = (short*)R;                                  // [NC*169,128]
  short* kb  = (short*)(R + (long)NC * 43264);
  short* vb  = (short*)(R + (long)NC * 86528);
  short* scb = (short*)(R + (long)NC * 129792);            // [NC,169,169]
  short* obp = (short*)(R + (long)NC * 187136);            // [NC*169,256]
  short* o2p = (short*)(R + (long)NC * 273664);            // [NC*169,256]
  short* ffh = qb;                                         // reuse (86528 <= q+k)
  short* o2b = obp;                                        // reuse

  // ---- weight conversion ----
  wcvt<<<1024, 256, 0, stream>>>(rfc1_W, rfc1p, 262144);
  wcvt<<<512, 256, 0, stream>>>(rfc2_W, rfc2p, 131072);
  wcvt<<<1536, 256, 0, stream>>>(t_inW, inWp, 393216);
  wcvt<<<512, 256, 0, stream>>>(t_outW, outWp, 131072);
  wcvt<<<512, 256, 0, stream>>>(t_ff1W, ff1p, 131072);
  wcvt<<<512, 256, 0, stream>>>(t_ff2W, ff2p, 131072);
  wcvt<<<1024, 256, 0, stream>>>(ffc_W, ffcp, 262144);
  wcvt<<<64, 256, 0, stream>>>(mu_W, mup, 16384);
  wcvt<<<64, 256, 0, stream>>>(lv_W, lvp, 16384);

  // ---- precompute ----
  pre_emb<<<58, 64, 0, stream>>>(emb_tile, ln_t_g, ln_t_b, emb_col, ln_c_g, ln_c_b,
                                 emb_row, ln_r_g, ln_r_b, te, ce, re);
  pre_fuse<<<201, 256, 0, stream>>>(te, ce, re, efus_W, efus_b, tf, pf);
  pre_gi<<<201, 256, 0, stream>>>(tf, pf, gru_Wi, gru_bi, tgi, pgi);
  pre_whpack<<<1536, 64, 0, stream>>>(gru_Wh, whpk);

  // ---- GRU scan ----
  gru_scan<<<64, 512, 0, stream>>>(x, tgi, pgi, whpk, gru_bh, hs);

  // ---- rfc head (chunked; Y overlay of hs is safe: writes stay below reads) ----
  for (int cb = 0; cb < 1024; cb += NC) {
    int C = NC * 169;
    const short* hsC = hs + (long)cb * 169 * 512;
    short* Yc = Y + (long)cb * 169 * 256;
    launch_gemm(stream, true, 1, false, hsC, 512, 0, rfc1p, 512, 0, rfc1_b, Uc, 512, 0, C, 512, 512, 1, 1);
    ln_gelu_512b<<<C / 4, 256, 0, stream>>>(Uc, rln_g, rln_b, C);
    launch_gemm(stream, true, 1, false, Uc, 512, 0, rfc2p, 512, 0, rfc2_b, Yc, 256, 0, C, 256, 512, 1, 1);
  }

  // ---- transformer: per-chunk, both layers (attention is within-batch) ----
  for (int cb = 0; cb < 1024; cb += NC) {
    int C = NC * 169;
    short* Yc = Y + (long)cb * 169 * 256;
    for (int i = 0; i < 2; i++) {
      const short* inWl = inWp + (long)i * 196608;
      const float* inbl = t_inb + i * 768;
      for (int h = 0; h < 2; h++) {
        launch_gemm(stream, true, 1, false, Yc, 256, 0, inWl + (0 + h * 128) * 256, 256, 0,
                    inbl + h * 128, qb, 128, 0, C, 128, 256, 1, 1);
        launch_gemm(stream, true, 1, false, Yc, 256, 0, inWl + (256 + h * 128) * 256, 256, 0,
                    inbl + 256 + h * 128, kb, 128, 0, C, 128, 256, 1, 1);
        launch_gemm(stream, true, 1, false, Yc, 256, 0, inWl + (512 + h * 128) * 256, 256, 0,
                    inbl + 512 + h * 128, vb, 128, 0, C, 128, 256, 1, 1);
        launch_gemm(stream, true, 0, false, qb, 128, 169 * 128, kb, 128, 169 * 128, nullptr,
                    scb, 169, 28561, 169, 169, 128, NC, 1);
        softmax_169b<<<(NC * 169) / 4, 256, 0, stream>>>(scb);
        launch_gemm(stream, false, 0, false, scb, 169, 28561, vb, 128, 169 * 128, nullptr,
                    obp + h * 128, 256, 43264, 169, 128, 169, NC, 0);
      }
      launch_gemm(stream, true, 1, false, obp, 256, 0, outWp + i * 65536, 256, 0, t_outb + i * 256,
                  o2p, 256, 0, C, 256, 256, 1, 1);
      res_lnb<<<C / 4, 256, 0, stream>>>(Yc, o2p, t_ln1g + i * 256, t_ln1b + i * 256);
      launch_gemm(stream, true, 2, false, Yc, 256, 0, ff1p + i * 65536, 256, 0, t_ff1b + i * 256,
                  ffh, 256, 0, C, 256, 256, 1, 1);
      launch_gemm(stream, true, 1, false, ffh, 256, 0, ff2p + i * 65536, 256, 0, t_ff2b + i * 256,
                  o2b, 256, 0, C, 256, 256, 1, 1);
      res_lnb<<<C / 4, 256, 0, stream>>>(Yc, o2b, t_ln2g + i * 256, t_ln2b + i * 256);
    }
  }

  // ---- final norm + pooling + heads ----
  final_poolb<<<1024, 256, 0, stream>>>(Y, fnorm_g, fnorm_b, hp);
  launch_gemm(stream, true, 1, false, hp, 512, 0, ffcp, 512, 0, ffc_b, h2, 512, 0, 1024, 512, 512, 1, 1);
  ln_gelu_512b<<<256, 256, 0, stream>>>(h2, ffc_lng, ffc_lnb, 1024);
  launch_gemm(stream, true, 1, true, h2, 512, 0, mup, 512, 0, mu_b, out, 32, 0, 1024, 32, 512, 1, 1);
  launch_gemm(stream, true, 1, true, h2, 512, 0, lvp, 512, 0, lv_b, out + 32768, 32, 0, 1024, 32, 512, 1, 1);
}

// Round 3
// 5646.094 us; speedup vs baseline: 1.4005x; 1.4005x over previous
//
#include <hip/hip_runtime.h>
#include <cmath>

// ============================================================================
// VAEEncoder on MI355X — round 3
//  * gemm_g: m97-structure (global_load_lds w16, pre-swizzled source, no guards)
//  * fused flash attention per (batch, head) — kills score/softmax/PV GEMMs
//  * one fused qkv GEMM per layer
//  * adaptive NC chunking incl. padded-M for NC=64/32
// ============================================================================

typedef __attribute__((ext_vector_type(8))) short bf16x8;
typedef __attribute__((ext_vector_type(4))) short s16x4;
typedef __attribute__((ext_vector_type(4))) float f32x4;

#define DEVINL __device__ __forceinline__

DEVINL short f2bf(float f) {
  union { float f; unsigned u; } v; v.f = f;
  unsigned r = v.u + 0x7fffu + ((v.u >> 16) & 1u);   // RNE
  return (short)(r >> 16);
}
DEVINL float bf2f(short s) {
  union { unsigned u; float f; } v; v.u = ((unsigned)(unsigned short)s) << 16; return v.f;
}
DEVINL float wred_sum(float v) {
  #pragma unroll
  for (int o = 32; o; o >>= 1) v += __shfl_xor(v, o);
  return v;
}
DEVINL float geluf(float x) { return 0.5f * x * (1.f + erff(x * 0.7071067811865475f)); }

DEVINL void gload16(const void* g, void* l) {
  __builtin_amdgcn_global_load_lds(
      (const __attribute__((address_space(1))) unsigned int*)g,
      (__attribute__((address_space(3))) unsigned int*)l, 16, 0, 0);
}

// ---------------------------------------------------------------------------
// all weight f32->bf16 conversions in one launch
// ---------------------------------------------------------------------------
struct WJobs { const float* s[7]; short* d[7]; int n[7]; };

__global__ __launch_bounds__(256) void wcvt_all(WJobs jb)
{
  int j = blockIdx.y;
  int i = blockIdx.x * 256 + threadIdx.x;
  if (i < jb.n[j]) jb.d[j][i] = f2bf(jb.s[j][i]);
}

// heads: pack mu/lv into padded [128,512] bf16 + combined bias[128]
__global__ __launch_bounds__(64) void prep_heads(
    const float* __restrict__ muW, const float* __restrict__ lvW,
    const float* __restrict__ mub, const float* __restrict__ lvb,
    short* __restrict__ Wp, float* __restrict__ bp)
{
  int r = blockIdx.x, t = threadIdx.x;
  for (int j = t; j < 512; j += 64) {
    float v = (r < 32) ? muW[r * 512 + j] : (r < 64) ? lvW[(r - 32) * 512 + j] : 0.f;
    Wp[r * 512 + j] = f2bf(v);
  }
  if (r == 0) bp[t] = (t < 32) ? mub[t] : lvb[t - 32];
  if (r == 1) bp[64 + t] = 0.f;
}

// ---------------------------------------------------------------------------
// pre1: te/ce/re = gelu(LN(row)) for 32+13+13 table rows
// ---------------------------------------------------------------------------
__global__ __launch_bounds__(64) void pre_emb(
    const float* __restrict__ emb_tile, const float* __restrict__ ltg, const float* __restrict__ ltb,
    const float* __restrict__ emb_col,  const float* __restrict__ lcg, const float* __restrict__ lcb,
    const float* __restrict__ emb_row,  const float* __restrict__ lrg, const float* __restrict__ lrb,
    float* __restrict__ te, float* __restrict__ ce, float* __restrict__ re)
{
  int r = blockIdx.x, l = threadIdx.x;
  const float *src, *g, *b; float* dst;
  if (r < 32)      { src = emb_tile + r * 128;       g = ltg; b = ltb; dst = te + r * 128; }
  else if (r < 45) { src = emb_col + (r - 32) * 128; g = lcg; b = lcb; dst = ce + (r - 32) * 128; }
  else             { src = emb_row + (r - 45) * 128; g = lrg; b = lrb; dst = re + (r - 45) * 128; }
  float v0 = src[l], v1 = src[64 + l];
  float m = wred_sum(v0 + v1) * (1.f / 128.f);
  float d0 = v0 - m, d1 = v1 - m;
  float var = wred_sum(d0 * d0 + d1 * d1) * (1.f / 128.f);
  float rstd = rsqrtf(var + 1e-5f);
  dst[l]      = geluf(d0 * rstd * g[l]      + b[l]);
  dst[64 + l] = geluf(d1 * rstd * g[64 + l] + b[64 + l]);
}

// ---------------------------------------------------------------------------
// pre2: tf[v][d] = te[v].efus_W[d,0:128] ; pf[s][d] = ce.W[d,128:256]+re.W[d,256:384]+eb[d]
// ---------------------------------------------------------------------------
__global__ __launch_bounds__(256) void pre_fuse(
    const float* __restrict__ te, const float* __restrict__ ce, const float* __restrict__ re,
    const float* __restrict__ W, const float* __restrict__ eb,
    float* __restrict__ tf, float* __restrict__ pf)
{
  __shared__ float buf[256];
  int r = blockIdx.x, t = threadIdx.x;
  if (r < 32) {
    if (t < 128) buf[t] = te[r * 128 + t];
    __syncthreads();
    float a = 0.f;
    for (int j = 0; j < 128; j++) a += buf[j] * W[t * 384 + j];
    tf[r * 256 + t] = a;
  } else {
    int s = r - 32, col = s % 13, row = s / 13;
    if (t < 128) buf[t] = ce[col * 128 + t];
    else         buf[t] = re[row * 128 + (t - 128)];
    __syncthreads();
    float a = eb[t];
    for (int j = 0; j < 128; j++) a += buf[j] * W[t * 384 + 128 + j];
    for (int j = 0; j < 128; j++) a += buf[128 + j] * W[t * 384 + 256 + j];
    pf[s * 256 + t] = a;
  }
}

// ---------------------------------------------------------------------------
// pre3: tgi[v][g] = tf[v].Wi[g,:] ; pgi[s][g] = pf[s].Wi[g,:] + bi[g]
// ---------------------------------------------------------------------------
__global__ __launch_bounds__(256) void pre_gi(
    const float* __restrict__ tf, const float* __restrict__ pf,
    const float* __restrict__ Wi, const float* __restrict__ bi,
    float* __restrict__ tgi, float* __restrict__ pgi)
{
  __shared__ float buf[256];
  int r = blockIdx.x, t = threadIdx.x;
  const float* src = (r < 32) ? tf + r * 256 : pf + (r - 32) * 256;
  buf[t] = src[t];
  __syncthreads();
  for (int gb = 0; gb < 1536; gb += 256) {
    int g = gb + t;
    float a = 0.f;
    for (int d = 0; d < 256; d++) a += buf[d] * Wi[(long)g * 256 + d];
    if (r < 32) tgi[r * 1536 + g] = a;
    else        pgi[(r - 32) * 1536 + g] = a + bi[g];
  }
}

// ---------------------------------------------------------------------------
// pre4: pack Wh [1536,512] f32 -> bf16 MFMA B-fragments
// ---------------------------------------------------------------------------
__global__ __launch_bounds__(64) void pre_whpack(const float* __restrict__ Wh, short* __restrict__ whpk)
{
  int kt = blockIdx.x / 96, ti = blockIdx.x % 96;
  int l = threadIdx.x;
  int gcol = ti * 16 + (l & 15);
  int kb = kt * 32 + (l >> 4) * 8;
  short* dst = whpk + ((long)(kt * 96 + ti) * 64 + l) * 8;
  #pragma unroll
  for (int j = 0; j < 8; j++) dst[j] = f2bf(Wh[(long)gcol * 512 + kb + j]);
}

// ---------------------------------------------------------------------------
// GRU scan: 64 blocks x 16 batches, 512 thr (unchanged from round 2; passed)
// ---------------------------------------------------------------------------
__global__ __launch_bounds__(512) void gru_scan(
    const int* __restrict__ x, const float* __restrict__ tgi, const float* __restrict__ pgi,
    const short* __restrict__ whpk, const float* __restrict__ bh, short* __restrict__ hs)
{
  __shared__ float h[16][520];
  __shared__ short hbf[16 * 512];   // (r,k) at r*512 + (k ^ ((r&7)<<3))
  __shared__ float bh_l[1536];
  int tid = threadIdx.x, w = tid >> 6, l = tid & 63;
  int lr = l & 15, lg = l >> 4;
  int b0 = blockIdx.x * 16;

  for (int i = tid; i < 16 * 520; i += 512) (&h[0][0])[i] = 0.f;
  for (int i = tid; i < 16 * 512; i += 512) hbf[i] = 0;
  for (int i = tid; i < 1536; i += 512) bh_l[i] = bh[i];
  __syncthreads();

  for (int s = 0; s < 169; s++) {
    int xv[4];
    #pragma unroll
    for (int i = 0; i < 4; i++) xv[i] = x[(b0 + lg * 4 + i) * 169 + s];
    float gi[12][4];
    #pragma unroll
    for (int j = 0; j < 12; j++) {
      int q = j >> 2, t = j & 3;
      int g = q * 512 + w * 64 + t * 16 + lr;
      float pg = pgi[s * 1536 + g];
      #pragma unroll
      for (int i = 0; i < 4; i++) gi[j][i] = tgi[xv[i] * 1536 + g] + pg;
    }
    f32x4 acc[12];
    #pragma unroll
    for (int j = 0; j < 12; j++) acc[j] = (f32x4){0.f, 0.f, 0.f, 0.f};
    #pragma unroll 2
    for (int kt = 0; kt < 16; kt++) {
      int ke = kt * 32 + lg * 8;
      bf16x8 af = *(const bf16x8*)&hbf[lr * 512 + (ke ^ ((lr & 7) << 3))];
      #pragma unroll
      for (int j = 0; j < 12; j++) {
        int q = j >> 2, t = j & 3;
        int ti = q * 32 + w * 4 + t;
        bf16x8 bfr = *(const bf16x8*)&whpk[((long)(kt * 96 + ti) * 64 + l) * 8];
        acc[j] = __builtin_amdgcn_mfma_f32_16x16x32_bf16(af, bfr, acc[j], 0, 0, 0);
      }
    }
    __syncthreads();
    #pragma unroll
    for (int t = 0; t < 4; t++) {
      int k = w * 64 + t * 16 + lr;
      float bhr = bh_l[k], bhz = bh_l[512 + k], bhn = bh_l[1024 + k];
      #pragma unroll
      for (int i = 0; i < 4; i++) {
        int row = lg * 4 + i;
        float r = 1.f / (1.f + expf(-(gi[0 * 4 + t][i] + acc[0 * 4 + t][i] + bhr)));
        float z = 1.f / (1.f + expf(-(gi[1 * 4 + t][i] + acc[1 * 4 + t][i] + bhz)));
        float n = tanhf(gi[2 * 4 + t][i] + r * (acc[2 * 4 + t][i] + bhn));
        float ho = h[row][k];
        float hn2 = (1.f - z) * n + z * ho;
        h[row][k] = hn2;
        short hv = f2bf(hn2);
        hbf[row * 512 + (k ^ ((row & 7) << 3))] = hv;
        hs[((long)(b0 + row) * 169 + s) * 512 + k] = hv;
      }
    }
    __syncthreads();
  }
}

// ---------------------------------------------------------------------------
// gemm_g: C[M,N] = A[M,K] @ B^T (+bias)(+relu). A,B bf16 row-major [M,K],[N,K].
// m97 structure: global_load_lds w16, linear LDS + pre-swizzled source so
// ds_reads are conflict-free. NO bounds in hot loop: M padded to 128 by the
// caller's scratch layout, N multiple of 128 (weights padded), K mult of 64.
// EPI: 1=+bias(bf16 out), 2=+bias+relu(bf16 out), 3=heads mapping (f32 out).
// ---------------------------------------------------------------------------
template <int EPI>
__global__ __launch_bounds__(256) void gemm_g(
    const short* __restrict__ A, int lda,
    const short* __restrict__ Bm, int ldb,
    const float* __restrict__ bias,
    void* __restrict__ Cv, int ldc,
    int M, int N, int K, int ntiles)
{
  __shared__ short a_lds[128 * 64];
  __shared__ short b_lds[128 * 64];
  int mt = blockIdx.x / ntiles, nt = blockIdx.x % ntiles;
  int m0 = mt * 128, n0 = nt * 128;
  int tid = threadIdx.x, w = tid >> 6, l = tid & 63;
  int wm = (w >> 1) * 64, wn = (w & 1) * 64;
  int lr = l & 15, lg = l >> 4;
  int row8 = l >> 3;                 // 0..7 within 8-row chunk
  int koff = (l & 7) * 8;            // shorts within 64-k row

  f32x4 acc[4][4];
  #pragma unroll
  for (int a = 0; a < 4; a++)
    #pragma unroll
    for (int b = 0; b < 4; b++) acc[a][b] = (f32x4){0.f, 0.f, 0.f, 0.f};

  for (int k0 = 0; k0 < K; k0 += 64) {
    __syncthreads();
    #pragma unroll
    for (int c = 0; c < 4; c++) {
      int r0 = (w * 4 + c) * 8;
      int ra = r0 + row8;
      int ks = koff ^ ((ra & 7) << 3);   // pre-swizzled source column
      gload16(A + (long)(m0 + ra) * lda + k0 + ks, &a_lds[r0 * 64]);
      gload16(Bm + (long)(n0 + ra) * ldb + k0 + ks, &b_lds[r0 * 64]);
    }
    __syncthreads();
    #pragma unroll
    for (int kt = 0; kt < 2; kt++) {
      int ke = kt * 32 + lg * 8;
      bf16x8 af[4], bfr[4];
      #pragma unroll
      for (int mi = 0; mi < 4; mi++) {
        int row = wm + mi * 16 + lr;
        af[mi] = *(const bf16x8*)&a_lds[row * 64 + (ke ^ ((row & 7) << 3))];
      }
      #pragma unroll
      for (int ni = 0; ni < 4; ni++) {
        int col = wn + ni * 16 + lr;
        bfr[ni] = *(const bf16x8*)&b_lds[col * 64 + (ke ^ ((col & 7) << 3))];
      }
      #pragma unroll
      for (int mi = 0; mi < 4; mi++)
        #pragma unroll
        for (int ni = 0; ni < 4; ni++)
          acc[mi][ni] = __builtin_amdgcn_mfma_f32_16x16x32_bf16(af[mi], bfr[ni], acc[mi][ni], 0, 0, 0);
    }
  }
  #pragma unroll
  for (int mi = 0; mi < 4; mi++) {
    #pragma unroll
    for (int ni = 0; ni < 4; ni++) {
      #pragma unroll
      for (int i = 0; i < 4; i++) {
        int row = m0 + wm + mi * 16 + lg * 4 + i;
        int col = n0 + wn + ni * 16 + lr;
        if (row < M) {
          if (EPI == 3) {
            if (col < 64) {
              float v = acc[mi][ni][i] + bias[col];
              long o = (col < 32) ? ((long)row * 32 + col) : (32768L + (long)row * 32 + col - 32);
              ((float*)Cv)[o] = v;
            }
          } else {
            float v = acc[mi][ni][i] + bias[col];
            if (EPI == 2) v = fmaxf(v, 0.f);
            ((short*)Cv)[(long)row * ldc + col] = f2bf(v);
          }
        }
      }
    }
  }
}

// ---------------------------------------------------------------------------
// fused flash attention: one block per (batch, head). S=169, D=128.
// K in LDS [176][128] (swz), V transposed in LDS [128][192] (swz),
// S' = mfma(K, Q) so softmax is lane-local over kk; P via per-wave LDS tile.
// ---------------------------------------------------------------------------
__global__ __launch_bounds__(256) void attn_fused(
    const short* __restrict__ qkv, short* __restrict__ ob)
{
  __shared__ short Kl[176 * 128];
  __shared__ short Vt[128 * 192];
  __shared__ short Pl[4][16 * 192];
  int b = blockIdx.x, h = blockIdx.y;
  const short* base = qkv + (long)b * 169 * 768;
  const short* Qp = base + h * 128;
  const short* Kp = base + 256 + h * 128;
  const short* Vp = base + 512 + h * 128;
  int tid = threadIdx.x, w = tid >> 6, l = tid & 63, lr = l & 15, lg = l >> 4;
  const float scale = 0.08838834764831845f;   // 1/sqrt(128)

  // stage K rows 0..175 (>=169 zero)
  for (int ch = tid; ch < 176 * 8; ch += 256) {
    int row = ch >> 3, kc = (ch & 7) * 8;
    bf16x8 v = (bf16x8){0, 0, 0, 0, 0, 0, 0, 0};
    if (row < 169) v = *(const bf16x8*)(Kp + (long)row * 768 + kc);
    *(bf16x8*)&Kl[row * 128 + (kc ^ ((row & 7) << 3))] = v;
  }
  // stage V transposed: Vt[d][kk]
  for (int ch = tid; ch < 169 * 16; ch += 256) {
    int kk = ch >> 4, d0 = (ch & 15) * 8;
    bf16x8 v = *(const bf16x8*)(Vp + (long)kk * 768 + d0);
    #pragma unroll
    for (int j = 0; j < 8; j++) {
      int d = d0 + j;
      Vt[d * 192 + (kk ^ ((d & 7) << 3))] = v[j];
    }
  }
  for (int i2 = tid; i2 < 128 * 23; i2 += 256) {
    int d = i2 / 23, kk = 169 + (i2 % 23);
    Vt[d * 192 + (kk ^ ((d & 7) << 3))] = 0;
  }
  __syncthreads();

  for (int qt = w; qt < 11; qt += 4) {
    int q0 = qt * 16;
    int qrow = q0 + lr; if (qrow > 168) qrow = 168;
    bf16x8 qf[4];
    #pragma unroll
    for (int ks = 0; ks < 4; ks++)
      qf[ks] = *(const bf16x8*)(Qp + (long)qrow * 768 + ks * 32 + lg * 8);
    // S'[kk, q] = sum_d K[kk,d] Q[q,d]
    f32x4 sacc[11];
    #pragma unroll
    for (int kt = 0; kt < 11; kt++) {
      sacc[kt] = (f32x4){0.f, 0.f, 0.f, 0.f};
      #pragma unroll
      for (int ks = 0; ks < 4; ks++) {
        int krow = kt * 16 + lr;
        bf16x8 kf = *(const bf16x8*)&Kl[krow * 128 + ((ks * 32 + lg * 8) ^ ((krow & 7) << 3))];
        sacc[kt] = __builtin_amdgcn_mfma_f32_16x16x32_bf16(kf, qf[ks], sacc[kt], 0, 0, 0);
      }
    }
    // softmax over kk (lane-local + 2 shuffles over lg bits)
    float sv[11][4];
    float mx = -1e30f;
    #pragma unroll
    for (int kt = 0; kt < 11; kt++)
      #pragma unroll
      for (int i = 0; i < 4; i++) {
        int kk = kt * 16 + lg * 4 + i;
        sv[kt][i] = (kk < 169) ? sacc[kt][i] * scale : -1e30f;
        mx = fmaxf(mx, sv[kt][i]);
      }
    mx = fmaxf(mx, __shfl_xor(mx, 16));
    mx = fmaxf(mx, __shfl_xor(mx, 32));
    float sum = 0.f;
    #pragma unroll
    for (int kt = 0; kt < 11; kt++)
      #pragma unroll
      for (int i = 0; i < 4; i++) {
        float e = (sv[kt][i] > -1e29f) ? expf(sv[kt][i] - mx) : 0.f;
        sv[kt][i] = e; sum += e;
      }
    sum += __shfl_xor(sum, 16);
    sum += __shfl_xor(sum, 32);
    float inv = 1.f / sum;
    // write P transposed: Pl[w][q=lr][kk]
    #pragma unroll
    for (int kt = 0; kt < 11; kt++)
      #pragma unroll
      for (int i = 0; i < 4; i++) {
        int kk = kt * 16 + lg * 4 + i;
        Pl[w][lr * 192 + (kk ^ ((lr & 7) << 3))] = f2bf(sv[kt][i] * inv);
      }
    if (lg == 0) {
      #pragma unroll
      for (int kk = 176; kk < 192; kk++)
        Pl[w][lr * 192 + (kk ^ ((lr & 7) << 3))] = 0;
    }
    asm volatile("s_waitcnt lgkmcnt(0)" ::: "memory");
    // O[q,d] = P @ V
    f32x4 oacc[8];
    #pragma unroll
    for (int dt = 0; dt < 8; dt++) oacc[dt] = (f32x4){0.f, 0.f, 0.f, 0.f};
    #pragma unroll
    for (int kt2 = 0; kt2 < 6; kt2++) {
      bf16x8 pf = *(const bf16x8*)&Pl[w][lr * 192 + ((kt2 * 32 + lg * 8) ^ ((lr & 7) << 3))];
      #pragma unroll
      for (int dt = 0; dt < 8; dt++) {
        int dr = dt * 16 + lr;
        bf16x8 vf = *(const bf16x8*)&Vt[dr * 192 + ((kt2 * 32 + lg * 8) ^ ((dr & 7) << 3))];
        oacc[dt] = __builtin_amdgcn_mfma_f32_16x16x32_bf16(pf, vf, oacc[dt], 0, 0, 0);
      }
    }
    #pragma unroll
    for (int dt = 0; dt < 8; dt++)
      #pragma unroll
      for (int i = 0; i < 4; i++) {
        int q = q0 + lg * 4 + i;
        if (q < 169)
          ob[((long)b * 169 + q) * 256 + h * 128 + dt * 16 + lr] = f2bf(oacc[dt][i]);
      }
  }
}

// ---------------------------------------------------------------------------
// elementwise / reduction (bf16 activations)
// ---------------------------------------------------------------------------
__global__ __launch_bounds__(256) void ln_gelu_512b(
    short* __restrict__ U, const float* __restrict__ g, const float* __restrict__ b, int nrows)
{
  int row = blockIdx.x * 4 + (threadIdx.x >> 6);
  if (row >= nrows) return;
  int l = threadIdx.x & 63;
  short* p = U + (long)row * 512;
  bf16x8 v = *(bf16x8*)(p + l * 8);
  float f[8];
  #pragma unroll
  for (int j = 0; j < 8; j++) f[j] = bf2f(v[j]);
  float s = 0.f;
  #pragma unroll
  for (int j = 0; j < 8; j++) s += f[j];
  float m = wred_sum(s) * (1.f / 512.f);
  float sq = 0.f;
  #pragma unroll
  for (int j = 0; j < 8; j++) { f[j] -= m; sq += f[j] * f[j]; }
  float rstd = rsqrtf(wred_sum(sq) * (1.f / 512.f) + 1e-5f);
  bf16x8 o;
  #pragma unroll
  for (int j = 0; j < 8; j++) o[j] = f2bf(geluf(f[j] * rstd * g[l * 8 + j] + b[l * 8 + j]));
  *(bf16x8*)(p + l * 8) = o;
}

__global__ __launch_bounds__(256) void res_lnb(
    short* __restrict__ y, const short* __restrict__ o,
    const float* __restrict__ g, const float* __restrict__ b)
{
  long row = (long)blockIdx.x * 4 + (threadIdx.x >> 6);
  int l = threadIdx.x & 63;
  short* p = y + row * 256;
  const short* q = o + row * 256;
  s16x4 yv = *(s16x4*)(p + l * 4);
  s16x4 ov = *(const s16x4*)(q + l * 4);
  float t[4];
  #pragma unroll
  for (int j = 0; j < 4; j++) t[j] = bf2f(yv[j]) + bf2f(ov[j]);
  float m = wred_sum(t[0] + t[1] + t[2] + t[3]) * (1.f / 256.f);
  float sq = 0.f;
  #pragma unroll
  for (int j = 0; j < 4; j++) { t[j] -= m; sq += t[j] * t[j]; }
  float rstd = rsqrtf(wred_sum(sq) * (1.f / 256.f) + 1e-5f);
  s16x4 wv;
  #pragma unroll
  for (int j = 0; j < 4; j++) wv[j] = f2bf(t[j] * rstd * g[l * 4 + j] + b[l * 4 + j]);
  *(s16x4*)(p + l * 4) = wv;
}

// final LN + mean/max pooling -> hp[b][0:256]=mean, [256:512]=max (bf16)
__global__ __launch_bounds__(256) void final_poolb(
    const short* __restrict__ y, const float* __restrict__ g, const float* __restrict__ b,
    short* __restrict__ hp)
{
  __shared__ float sm[4][256], sx[4][256];
  int bb = blockIdx.x;
  int w = threadIdx.x >> 6, l = threadIdx.x & 63;
  float am[4] = {0.f, 0.f, 0.f, 0.f};
  float ax[4] = {-3.4e38f, -3.4e38f, -3.4e38f, -3.4e38f};
  float gl[4], bl[4];
  #pragma unroll
  for (int j = 0; j < 4; j++) { gl[j] = g[l * 4 + j]; bl[j] = b[l * 4 + j]; }
  for (int s = w; s < 169; s += 4) {
    s16x4 vv = *(const s16x4*)(y + ((long)bb * 169 + s) * 256 + l * 4);
    float t[4];
    #pragma unroll
    for (int j = 0; j < 4; j++) t[j] = bf2f(vv[j]);
    float m = wred_sum(t[0] + t[1] + t[2] + t[3]) * (1.f / 256.f);
    float sq = 0.f;
    #pragma unroll
    for (int j = 0; j < 4; j++) { t[j] -= m; sq += t[j] * t[j]; }
    float rstd = rsqrtf(wred_sum(sq) * (1.f / 256.f) + 1e-5f);
    #pragma unroll
    for (int j = 0; j < 4; j++) {
      float o = t[j] * rstd * gl[j] + bl[j];
      am[j] += o; ax[j] = fmaxf(ax[j], o);
    }
  }
  #pragma unroll
  for (int j = 0; j < 4; j++) { sm[w][l * 4 + j] = am[j]; sx[w][l * 4 + j] = ax[j]; }
  __syncthreads();
  if (w == 0) {
    #pragma unroll
    for (int j = 0; j < 4; j++) {
      int c = l * 4 + j;
      float ms = sm[0][c] + sm[1][c] + sm[2][c] + sm[3][c];
      float mx = fmaxf(fmaxf(sx[0][c], sx[1][c]), fmaxf(sx[2][c], sx[3][c]));
      hp[(long)bb * 512 + c] = f2bf(ms * (1.f / 169.f));
      hp[(long)bb * 512 + 256 + c] = f2bf(mx);
    }
  }
}

// ---------------------------------------------------------------------------
// host
// ---------------------------------------------------------------------------
extern "C" void kernel_launch(void* const* d_in, const int* in_sizes, int n_in,
                              void* d_out, int out_size, void* d_ws, size_t ws_size,
                              hipStream_t stream)
{
  const int*   x        = (const int*)d_in[0];
  const float* emb_tile = (const float*)d_in[1];
  const float* ln_t_g   = (const float*)d_in[2];
  const float* ln_t_b   = (const float*)d_in[3];
  const float* emb_col  = (const float*)d_in[4];
  const float* ln_c_g   = (const float*)d_in[5];
  const float* ln_c_b   = (const float*)d_in[6];
  const float* emb_row  = (const float*)d_in[7];
  const float* ln_r_g   = (const float*)d_in[8];
  const float* ln_r_b   = (const float*)d_in[9];
  const float* efus_W   = (const float*)d_in[10];
  const float* efus_b   = (const float*)d_in[11];
  const float* gru_Wi   = (const float*)d_in[12];
  const float* gru_Wh   = (const float*)d_in[13];
  const float* gru_bi   = (const float*)d_in[14];
  const float* gru_bh   = (const float*)d_in[15];
  const float* rfc1_W   = (const float*)d_in[16];
  const float* rfc1_b   = (const float*)d_in[17];
  const float* rln_g    = (const float*)d_in[18];
  const float* rln_b    = (const float*)d_in[19];
  const float* rfc2_W   = (const float*)d_in[20];
  const float* rfc2_b   = (const float*)d_in[21];
  const float* t_inW    = (const float*)d_in[22];
  const float* t_inb    = (const float*)d_in[23];
  const float* t_outW   = (const float*)d_in[24];
  const float* t_outb   = (const float*)d_in[25];
  const float* t_ln1g   = (const float*)d_in[26];
  const float* t_ln1b   = (const float*)d_in[27];
  const float* t_ff1W   = (const float*)d_in[28];
  const float* t_ff1b   = (const float*)d_in[29];
  const float* t_ff2W   = (const float*)d_in[30];
  const float* t_ff2b   = (const float*)d_in[31];
  const float* t_ln2g   = (const float*)d_in[32];
  const float* t_ln2b   = (const float*)d_in[33];
  const float* fnorm_g  = (const float*)d_in[34];
  const float* fnorm_b  = (const float*)d_in[35];
  const float* ffc_W    = (const float*)d_in[36];
  const float* ffc_b    = (const float*)d_in[37];
  const float* ffc_lng  = (const float*)d_in[38];
  const float* ffc_lnb  = (const float*)d_in[39];
  const float* mu_W     = (const float*)d_in[40];
  const float* mu_b     = (const float*)d_in[41];
  const float* lv_W     = (const float*)d_in[42];
  const float* lv_b     = (const float*)d_in[43];
  float* out = (float*)d_out;

  char* ws = (char*)d_ws;

  // ---- small region ----
  float* te      = (float*)(ws + 0);
  float* ce      = (float*)(ws + 16384);
  float* re      = (float*)(ws + 23040);
  float* tf      = (float*)(ws + 29696);
  float* pf      = (float*)(ws + 62464);
  float* tgi     = (float*)(ws + 235520);
  float* pgi     = (float*)(ws + 432128);
  short* whpk    = (short*)(ws + 1470464);
  short* wp      = (short*)(ws + 3043328);      // 1441792 bf16
  short* headsWp = (short*)(ws + 5926912);      // 128*512 bf16
  float* headsB  = (float*)(ws + 6057984);      // 128 f32
  short* hp      = (short*)(ws + 6058496);      // wait for alignment: 6058496 % 16 == 0
  short* h2      = (short*)(ws + 7107072);

  short* rfc1p = wp;
  short* rfc2p = wp + 262144;
  short* inWp  = wp + 393216;
  short* outWp = wp + 786432;
  short* ff1p  = wp + 917504;
  short* ff2p  = wp + 1048576;
  short* ffcp  = wp + 1179648;

  // ---- big region: hs [173056,512] bf16; Y overlays hs (safe by chunk order) ----
  const size_t o_hs = 8388608;
  short* hs = (short*)(ws + o_hs);
  short* Y  = hs;
  const size_t o_R = o_hs + 177209344ULL;

  // ---- adaptive chunk: NC batches/chunk, M padded to 128 ----
  size_t Ravail = ws_size > o_R ? ws_size - o_R : 0;
  int NC = 1024;
  while (NC > 32) {
    long Mp_t = (((long)NC * 169 + 127) / 128) * 128;
    if ((size_t)Mp_t * 2560 <= Ravail) break;
    NC >>= 1;
  }
  const long Mp = (((long)NC * 169 + 127) / 128) * 128;
  char* R = ws + o_R;
  short* qkvb = (short*)R;                         // [Mp,768]
  short* obp  = (short*)(R + Mp * 1536);           // [Mp,256]
  short* o2p  = (short*)(R + Mp * 2048);           // [Mp,256]
  short* Uc   = (short*)R;                         // [Mp,512] (rfc phase)
  short* ffh  = qkvb;                              // ff hidden (reuse)
  short* o2b  = obp;                               // ff2 out (reuse)

  // ---- weight conversions (1 launch) + heads pack ----
  WJobs jb;
  jb.s[0] = rfc1_W;  jb.d[0] = rfc1p; jb.n[0] = 262144;
  jb.s[1] = rfc2_W;  jb.d[1] = rfc2p; jb.n[1] = 131072;
  jb.s[2] = t_inW;   jb.d[2] = inWp;  jb.n[2] = 393216;
  jb.s[3] = t_outW;  jb.d[3] = outWp; jb.n[3] = 131072;
  jb.s[4] = t_ff1W;  jb.d[4] = ff1p;  jb.n[4] = 131072;
  jb.s[5] = t_ff2W;  jb.d[5] = ff2p;  jb.n[5] = 131072;
  jb.s[6] = ffc_W;   jb.d[6] = ffcp;  jb.n[6] = 262144;
  wcvt_all<<<dim3(1536, 7), 256, 0, stream>>>(jb);
  prep_heads<<<128, 64, 0, stream>>>(mu_W, lv_W, mu_b, lv_b, headsWp, headsB);

  // ---- precompute ----
  pre_emb<<<58, 64, 0, stream>>>(emb_tile, ln_t_g, ln_t_b, emb_col, ln_c_g, ln_c_b,
                                 emb_row, ln_r_g, ln_r_b, te, ce, re);
  pre_fuse<<<201, 256, 0, stream>>>(te, ce, re, efus_W, efus_b, tf, pf);
  pre_gi<<<201, 256, 0, stream>>>(tf, pf, gru_Wi, gru_bi, tgi, pgi);
  pre_whpack<<<1536, 64, 0, stream>>>(gru_Wh, whpk);

  // ---- GRU scan ----
  gru_scan<<<64, 512, 0, stream>>>(x, tgi, pgi, whpk, gru_bh, hs);

  const int MT = (int)(Mp / 128);

  // ---- rfc head ----
  for (int cb = 0; cb < 1024; cb += NC) {
    int C = NC * 169;
    const short* hsC = hs + (long)cb * 169 * 512;
    short* Yc = Y + (long)cb * 169 * 256;
    gemm_g<1><<<MT * 4, 256, 0, stream>>>(hsC, 512, rfc1p, 512, rfc1_b, Uc, 512, C, 512, 512, 4);
    ln_gelu_512b<<<C / 4, 256, 0, stream>>>(Uc, rln_g, rln_b, C);
    gemm_g<1><<<MT * 2, 256, 0, stream>>>(Uc, 512, rfc2p, 512, rfc2_b, Yc, 256, C, 256, 512, 2);
  }

  // ---- transformer ----
  for (int cb = 0; cb < 1024; cb += NC) {
    int C = NC * 169;
    short* Yc = Y + (long)cb * 169 * 256;
    for (int i = 0; i < 2; i++) {
      gemm_g<1><<<MT * 6, 256, 0, stream>>>(Yc, 256, inWp + (long)i * 196608, 256,
                                            t_inb + i * 768, qkvb, 768, C, 768, 256, 6);
      attn_fused<<<dim3(NC, 2), 256, 0, stream>>>(qkvb, obp);
      gemm_g<1><<<MT * 2, 256, 0, stream>>>(obp, 256, outWp + i * 65536, 256,
                                            t_outb + i * 256, o2p, 256, C, 256, 256, 2);
      res_lnb<<<C / 4, 256, 0, stream>>>(Yc, o2p, t_ln1g + i * 256, t_ln1b + i * 256);
      gemm_g<2><<<MT * 2, 256, 0, stream>>>(Yc, 256, ff1p + i * 65536, 256,
                                            t_ff1b + i * 256, ffh, 256, C, 256, 256, 2);
      gemm_g<1><<<MT * 2, 256, 0, stream>>>(ffh, 256, ff2p + i * 65536, 256,
                                            t_ff2b + i * 256, o2b, 256, C, 256, 256, 2);
      res_lnb<<<C / 4, 256, 0, stream>>>(Yc, o2b, t_ln2g + i * 256, t_ln2b + i * 256);
    }
  }

  // ---- final norm + pooling + heads ----
  final_poolb<<<1024, 256, 0, stream>>>(Y, fnorm_g, fnorm_b, hp);
  gemm_g<1><<<8 * 4, 256, 0, stream>>>(hp, 512, ffcp, 512, ffc_b, h2, 512, 1024, 512, 512, 4);
  ln_gelu_512b<<<256, 256, 0, stream>>>(h2, ffc_lng, ffc_lnb, 1024);
  gemm_g<3><<<8 * 1, 256, 0, stream>>>(h2, 512, headsWp, 512, headsB, out, 0, 1024, 128, 512, 1);
}

// Round 4
// 5193.839 us; speedup vs baseline: 1.5224x; 1.0871x over previous
//
#include <hip/hip_runtime.h>
#include <cmath>

// ============================================================================
// VAEEncoder on MI355X — round 4
//  * gru_scan4: gate-quarter split across 256 blocks (4 blocks per batch-group)
//    - each block streams only 1/4 of the Wh pack per step (L2-link bound fix)
//    - per-step h-slice exchange via agent-scope atomics + release/acquire flags
//  * rest identical to round 3 (passed, absmax 0.0078)
// ============================================================================

typedef __attribute__((ext_vector_type(8))) short bf16x8;
typedef __attribute__((ext_vector_type(4))) short s16x4;
typedef __attribute__((ext_vector_type(4))) float f32x4;

#define DEVINL __device__ __forceinline__

DEVINL short f2bf(float f) {
  union { float f; unsigned u; } v; v.f = f;
  unsigned r = v.u + 0x7fffu + ((v.u >> 16) & 1u);   // RNE
  return (short)(r >> 16);
}
DEVINL float bf2f(short s) {
  union { unsigned u; float f; } v; v.u = ((unsigned)(unsigned short)s) << 16; return v.f;
}
DEVINL float wred_sum(float v) {
  #pragma unroll
  for (int o = 32; o; o >>= 1) v += __shfl_xor(v, o);
  return v;
}
DEVINL float geluf(float x) { return 0.5f * x * (1.f + erff(x * 0.7071067811865475f)); }
DEVINL float sigm(float x) { return 1.f / (1.f + __expf(-x)); }
DEVINL float tanh_fast(float x) { return 1.f - 2.f / (__expf(2.f * x) + 1.f); }

DEVINL void gload16(const void* g, void* l) {
  __builtin_amdgcn_global_load_lds(
      (const __attribute__((address_space(1))) unsigned int*)g,
      (__attribute__((address_space(3))) unsigned int*)l, 16, 0, 0);
}

// ---------------------------------------------------------------------------
// all weight f32->bf16 conversions in one launch
// ---------------------------------------------------------------------------
struct WJobs { const float* s[7]; short* d[7]; int n[7]; };

__global__ __launch_bounds__(256) void wcvt_all(WJobs jb)
{
  int j = blockIdx.y;
  int i = blockIdx.x * 256 + threadIdx.x;
  if (i < jb.n[j]) jb.d[j][i] = f2bf(jb.s[j][i]);
}

// heads: pack mu/lv into padded [128,512] bf16 + combined bias[128]
__global__ __launch_bounds__(64) void prep_heads(
    const float* __restrict__ muW, const float* __restrict__ lvW,
    const float* __restrict__ mub, const float* __restrict__ lvb,
    short* __restrict__ Wp, float* __restrict__ bp)
{
  int r = blockIdx.x, t = threadIdx.x;
  for (int j = t; j < 512; j += 64) {
    float v = (r < 32) ? muW[r * 512 + j] : (r < 64) ? lvW[(r - 32) * 512 + j] : 0.f;
    Wp[r * 512 + j] = f2bf(v);
  }
  if (r == 0) bp[t] = (t < 32) ? mub[t] : lvb[t - 32];
  if (r == 1) bp[64 + t] = 0.f;
}

// ---------------------------------------------------------------------------
// pre1: te/ce/re = gelu(LN(row)) for 32+13+13 table rows
// ---------------------------------------------------------------------------
__global__ __launch_bounds__(64) void pre_emb(
    const float* __restrict__ emb_tile, const float* __restrict__ ltg, const float* __restrict__ ltb,
    const float* __restrict__ emb_col,  const float* __restrict__ lcg, const float* __restrict__ lcb,
    const float* __restrict__ emb_row,  const float* __restrict__ lrg, const float* __restrict__ lrb,
    float* __restrict__ te, float* __restrict__ ce, float* __restrict__ re)
{
  int r = blockIdx.x, l = threadIdx.x;
  const float *src, *g, *b; float* dst;
  if (r < 32)      { src = emb_tile + r * 128;       g = ltg; b = ltb; dst = te + r * 128; }
  else if (r < 45) { src = emb_col + (r - 32) * 128; g = lcg; b = lcb; dst = ce + (r - 32) * 128; }
  else             { src = emb_row + (r - 45) * 128; g = lrg; b = lrb; dst = re + (r - 45) * 128; }
  float v0 = src[l], v1 = src[64 + l];
  float m = wred_sum(v0 + v1) * (1.f / 128.f);
  float d0 = v0 - m, d1 = v1 - m;
  float var = wred_sum(d0 * d0 + d1 * d1) * (1.f / 128.f);
  float rstd = rsqrtf(var + 1e-5f);
  dst[l]      = geluf(d0 * rstd * g[l]      + b[l]);
  dst[64 + l] = geluf(d1 * rstd * g[64 + l] + b[64 + l]);
}

// ---------------------------------------------------------------------------
// pre2
// ---------------------------------------------------------------------------
__global__ __launch_bounds__(256) void pre_fuse(
    const float* __restrict__ te, const float* __restrict__ ce, const float* __restrict__ re,
    const float* __restrict__ W, const float* __restrict__ eb,
    float* __restrict__ tf, float* __restrict__ pf)
{
  __shared__ float buf[256];
  int r = blockIdx.x, t = threadIdx.x;
  if (r < 32) {
    if (t < 128) buf[t] = te[r * 128 + t];
    __syncthreads();
    float a = 0.f;
    for (int j = 0; j < 128; j++) a += buf[j] * W[t * 384 + j];
    tf[r * 256 + t] = a;
  } else {
    int s = r - 32, col = s % 13, row = s / 13;
    if (t < 128) buf[t] = ce[col * 128 + t];
    else         buf[t] = re[row * 128 + (t - 128)];
    __syncthreads();
    float a = eb[t];
    for (int j = 0; j < 128; j++) a += buf[j] * W[t * 384 + 128 + j];
    for (int j = 0; j < 128; j++) a += buf[128 + j] * W[t * 384 + 256 + j];
    pf[s * 256 + t] = a;
  }
}

// ---------------------------------------------------------------------------
// pre3
// ---------------------------------------------------------------------------
__global__ __launch_bounds__(256) void pre_gi(
    const float* __restrict__ tf, const float* __restrict__ pf,
    const float* __restrict__ Wi, const float* __restrict__ bi,
    float* __restrict__ tgi, float* __restrict__ pgi)
{
  __shared__ float buf[256];
  int r = blockIdx.x, t = threadIdx.x;
  const float* src = (r < 32) ? tf + r * 256 : pf + (r - 32) * 256;
  buf[t] = src[t];
  __syncthreads();
  for (int gb = 0; gb < 1536; gb += 256) {
    int g = gb + t;
    float a = 0.f;
    for (int d = 0; d < 256; d++) a += buf[d] * Wi[(long)g * 256 + d];
    if (r < 32) tgi[r * 1536 + g] = a;
    else        pgi[(r - 32) * 1536 + g] = a + bi[g];
  }
}

// ---------------------------------------------------------------------------
// pre4: pack Wh -> bf16 fragments grouped by (qk, q, wave, kt) for gru_scan4
//   block bi in [0,1536): kt = bi & 15; tc = bi >> 4; wv = tc & 7; qc = tc >> 3;
//   q = qc % 3, qk = qc / 3; gate = q*512 + qk*128 + wv*16 + (l&15)
// ---------------------------------------------------------------------------
__global__ __launch_bounds__(64) void pre_whpack2(const float* __restrict__ Wh, short* __restrict__ whpk)
{
  int bi = blockIdx.x;
  int kt = bi & 15, tc = bi >> 4;
  int wv = tc & 7, qc = tc >> 3;
  int q = qc % 3, qk = qc / 3;
  int l = threadIdx.x;
  int gate = q * 512 + qk * 128 + wv * 16 + (l & 15);
  int kb = kt * 32 + (l >> 4) * 8;
  short* dst = whpk + ((long)bi * 64 + l) * 8;
  #pragma unroll
  for (int j = 0; j < 8; j++) dst[j] = f2bf(Wh[(long)gate * 512 + kb + j]);
}

// ---------------------------------------------------------------------------
// gru_scan4: 256 blocks = 64 batch-groups x 4 gate-quarters, 512 thr (8 waves).
// Block (g,qk): 16 batches, gates {r,z,n} x k-slice [qk*128, qk*128+128).
// Per step: stream 0.39 MB Wh quarter; exchange h-slices via hx (u64 agent
// atomics) + flags (release/acquire). bid = qk*64 + g (partners same XCD mod 8).
// ---------------------------------------------------------------------------
__global__ __launch_bounds__(512) void gru_scan4(
    const int* __restrict__ x, const float* __restrict__ tgi, const float* __restrict__ pgi,
    const short* __restrict__ whpk, const float* __restrict__ bh, short* __restrict__ hs,
    unsigned long long* __restrict__ hx, int* __restrict__ flags)
{
  __shared__ float hq[16][132];     // own k-slice master (f32)
  __shared__ short hbf[16 * 512];   // full h bf16: (r,k) at r*512 + (k ^ ((r&7)<<3))
  __shared__ float bh_l[3][128];

  int bid = blockIdx.x;
  int qk = bid >> 6, g = bid & 63;
  int b0 = g * 16;
  int tid = threadIdx.x, w = tid >> 6, l = tid & 63, lr = l & 15, lg = l >> 4;

  for (int i = tid; i < 16 * 132; i += 512) (&hq[0][0])[i] = 0.f;
  for (int i = tid; i < 16 * 512; i += 512) hbf[i] = 0;
  if (tid < 384) bh_l[tid >> 7][tid & 127] = bh[(tid >> 7) * 512 + qk * 128 + (tid & 127)];
  __syncthreads();

  // per-wave fragment bases: tile (qk, q, w), kt-major inside
  const short* wq[3];
  #pragma unroll
  for (int q = 0; q < 3; q++)
    wq[q] = whpk + ((long)(((qk * 3 + q) * 8 + w) * 16) * 64 + l) * 8;

  const int o = qk * 4;               // own kt range [o, o+4)
  const int kk = w * 16 + lr;         // own-slice k index [0,128)
  const int kglob = qk * 128 + kk;

  for (int s = 0; s < 169; s++) {
    // ---- gate-input gathers (independent of h) ----
    int xv[4];
    #pragma unroll
    for (int i = 0; i < 4; i++) xv[i] = x[(b0 + lg * 4 + i) * 169 + s];
    float gi[3][4];
    #pragma unroll
    for (int q = 0; q < 3; q++) {
      int gate = q * 512 + qk * 128 + kk;
      float pg = pgi[s * 1536 + gate];
      #pragma unroll
      for (int i = 0; i < 4; i++) gi[q][i] = tgi[xv[i] * 1536 + gate] + pg;
    }
    // ---- wait for the 3 partner quarters to publish h(s-1) ----
    if (tid < 3) {
      int p = tid < qk ? tid : tid + 1;
      while (__hip_atomic_load(&flags[p * 64 + g], __ATOMIC_ACQUIRE,
                               __HIP_MEMORY_SCOPE_AGENT) < s)
        __builtin_amdgcn_s_sleep(16);
    }
    __syncthreads();   // B1: partners ready; prev update's hbf writes visible
    // ---- issue foreign h loads (hide under own-k MFMA) ----
    unsigned long long fv[3]; int fks[3];
    #pragma unroll
    for (int p = 0; p < 3; p++) {
      int idx = tid + p * 512;
      int fk = idx >> 2;
      int k = fk < qk * 128 ? fk : fk + 128;
      fks[p] = k;
      fv[p] = __hip_atomic_load(&hx[((long)g * 512 + k) * 4 + (idx & 3)],
                                __ATOMIC_RELAXED, __HIP_MEMORY_SCOPE_AGENT);
    }
    // ---- own-k MFMA ----
    f32x4 acc[3];
    #pragma unroll
    for (int q = 0; q < 3; q++) acc[q] = (f32x4){0.f, 0.f, 0.f, 0.f};
    #pragma unroll
    for (int kt = 0; kt < 4; kt++) {
      int kte = o + kt;
      bf16x8 af = *(const bf16x8*)&hbf[lr * 512 + ((kte * 32 + lg * 8) ^ ((lr & 7) << 3))];
      #pragma unroll
      for (int q = 0; q < 3; q++) {
        bf16x8 bfr = *(const bf16x8*)(wq[q] + (long)kte * 512);
        acc[q] = __builtin_amdgcn_mfma_f32_16x16x32_bf16(af, bfr, acc[q], 0, 0, 0);
      }
    }
    // ---- deposit foreign h into hbf ----
    #pragma unroll
    for (int p = 0; p < 3; p++) {
      int idx = tid + p * 512;
      int k = fks[p];
      int r4 = (idx & 3) * 4;
      unsigned long long v = fv[p];
      #pragma unroll
      for (int j = 0; j < 4; j++) {
        int row = r4 + j;
        hbf[row * 512 + (k ^ ((row & 7) << 3))] = (short)(v >> (16 * j));
      }
    }
    __syncthreads();   // B2: foreign hbf complete
    // ---- foreign-k MFMA ----
    #pragma unroll 4
    for (int kto = 0; kto < 12; kto++) {
      int kt = kto < o ? kto : kto + 4;
      bf16x8 af = *(const bf16x8*)&hbf[lr * 512 + ((kt * 32 + lg * 8) ^ ((lr & 7) << 3))];
      #pragma unroll
      for (int q = 0; q < 3; q++) {
        bf16x8 bfr = *(const bf16x8*)(wq[q] + (long)kt * 512);
        acc[q] = __builtin_amdgcn_mfma_f32_16x16x32_bf16(af, bfr, acc[q], 0, 0, 0);
      }
    }
    __syncthreads();   // B3: all hbf reads done before update writes
    // ---- gates + h update (own k-slice) ----
    float bhr = bh_l[0][kk], bhz = bh_l[1][kk], bhn = bh_l[2][kk];
    unsigned short us[4];
    #pragma unroll
    for (int i = 0; i < 4; i++) {
      int row = lg * 4 + i;
      float r = sigm(gi[0][i] + acc[0][i] + bhr);
      float z = sigm(gi[1][i] + acc[1][i] + bhz);
      float n = tanh_fast(gi[2][i] + r * (acc[2][i] + bhn));
      float ho = hq[row][kk];
      float hn2 = (1.f - z) * n + z * ho;
      hq[row][kk] = hn2;
      short hv = f2bf(hn2);
      hbf[row * 512 + (kglob ^ ((row & 7) << 3))] = hv;
      hs[((long)(b0 + row) * 169 + s) * 512 + kglob] = hv;
      us[i] = (unsigned short)hv;
    }
    unsigned long long pk = (unsigned long long)us[0] | ((unsigned long long)us[1] << 16) |
                            ((unsigned long long)us[2] << 32) | ((unsigned long long)us[3] << 48);
    __hip_atomic_store(&hx[((long)g * 512 + kglob) * 4 + lg], pk,
                       __ATOMIC_RELAXED, __HIP_MEMORY_SCOPE_AGENT);
    __syncthreads();   // B4: all waves' hx stores retired (vmcnt 0)
    if (tid == 0)
      __hip_atomic_store(&flags[qk * 64 + g], s + 1,
                         __ATOMIC_RELEASE, __HIP_MEMORY_SCOPE_AGENT);
  }
}

// ---------------------------------------------------------------------------
// gemm_g (unchanged from round 3)
// ---------------------------------------------------------------------------
template <int EPI>
__global__ __launch_bounds__(256) void gemm_g(
    const short* __restrict__ A, int lda,
    const short* __restrict__ Bm, int ldb,
    const float* __restrict__ bias,
    void* __restrict__ Cv, int ldc,
    int M, int N, int K, int ntiles)
{
  __shared__ short a_lds[128 * 64];
  __shared__ short b_lds[128 * 64];
  int mt = blockIdx.x / ntiles, nt = blockIdx.x % ntiles;
  int m0 = mt * 128, n0 = nt * 128;
  int tid = threadIdx.x, w = tid >> 6, l = tid & 63;
  int wm = (w >> 1) * 64, wn = (w & 1) * 64;
  int lr = l & 15, lg = l >> 4;
  int row8 = l >> 3;
  int koff = (l & 7) * 8;

  f32x4 acc[4][4];
  #pragma unroll
  for (int a = 0; a < 4; a++)
    #pragma unroll
    for (int b = 0; b < 4; b++) acc[a][b] = (f32x4){0.f, 0.f, 0.f, 0.f};

  for (int k0 = 0; k0 < K; k0 += 64) {
    __syncthreads();
    #pragma unroll
    for (int c = 0; c < 4; c++) {
      int r0 = (w * 4 + c) * 8;
      int ra = r0 + row8;
      int ks = koff ^ ((ra & 7) << 3);
      gload16(A + (long)(m0 + ra) * lda + k0 + ks, &a_lds[r0 * 64]);
      gload16(Bm + (long)(n0 + ra) * ldb + k0 + ks, &b_lds[r0 * 64]);
    }
    __syncthreads();
    #pragma unroll
    for (int kt = 0; kt < 2; kt++) {
      int ke = kt * 32 + lg * 8;
      bf16x8 af[4], bfr[4];
      #pragma unroll
      for (int mi = 0; mi < 4; mi++) {
        int row = wm + mi * 16 + lr;
        af[mi] = *(const bf16x8*)&a_lds[row * 64 + (ke ^ ((row & 7) << 3))];
      }
      #pragma unroll
      for (int ni = 0; ni < 4; ni++) {
        int col = wn + ni * 16 + lr;
        bfr[ni] = *(const bf16x8*)&b_lds[col * 64 + (ke ^ ((col & 7) << 3))];
      }
      #pragma unroll
      for (int mi = 0; mi < 4; mi++)
        #pragma unroll
        for (int ni = 0; ni < 4; ni++)
          acc[mi][ni] = __builtin_amdgcn_mfma_f32_16x16x32_bf16(af[mi], bfr[ni], acc[mi][ni], 0, 0, 0);
    }
  }
  #pragma unroll
  for (int mi = 0; mi < 4; mi++) {
    #pragma unroll
    for (int ni = 0; ni < 4; ni++) {
      #pragma unroll
      for (int i = 0; i < 4; i++) {
        int row = m0 + wm + mi * 16 + lg * 4 + i;
        int col = n0 + wn + ni * 16 + lr;
        if (row < M) {
          if (EPI == 3) {
            if (col < 64) {
              float v = acc[mi][ni][i] + bias[col];
              long o = (col < 32) ? ((long)row * 32 + col) : (32768L + (long)row * 32 + col - 32);
              ((float*)Cv)[o] = v;
            }
          } else {
            float v = acc[mi][ni][i] + bias[col];
            if (EPI == 2) v = fmaxf(v, 0.f);
            ((short*)Cv)[(long)row * ldc + col] = f2bf(v);
          }
        }
      }
    }
  }
}

// ---------------------------------------------------------------------------
// fused flash attention (unchanged from round 3)
// ---------------------------------------------------------------------------
__global__ __launch_bounds__(256) void attn_fused(
    const short* __restrict__ qkv, short* __restrict__ ob)
{
  __shared__ short Kl[176 * 128];
  __shared__ short Vt[128 * 192];
  __shared__ short Pl[4][16 * 192];
  int b = blockIdx.x, h = blockIdx.y;
  const short* base = qkv + (long)b * 169 * 768;
  const short* Qp = base + h * 128;
  const short* Kp = base + 256 + h * 128;
  const short* Vp = base + 512 + h * 128;
  int tid = threadIdx.x, w = tid >> 6, l = tid & 63, lr = l & 15, lg = l >> 4;
  const float scale = 0.08838834764831845f;

  for (int ch = tid; ch < 176 * 8; ch += 256) {
    int row = ch >> 3, kc = (ch & 7) * 8;
    bf16x8 v = (bf16x8){0, 0, 0, 0, 0, 0, 0, 0};
    if (row < 169) v = *(const bf16x8*)(Kp + (long)row * 768 + kc);
    *(bf16x8*)&Kl[row * 128 + (kc ^ ((row & 7) << 3))] = v;
  }
  for (int ch = tid; ch < 169 * 16; ch += 256) {
    int kk = ch >> 4, d0 = (ch & 15) * 8;
    bf16x8 v = *(const bf16x8*)(Vp + (long)kk * 768 + d0);
    #pragma unroll
    for (int j = 0; j < 8; j++) {
      int d = d0 + j;
      Vt[d * 192 + (kk ^ ((d & 7) << 3))] = v[j];
    }
  }
  for (int i2 = tid; i2 < 128 * 23; i2 += 256) {
    int d = i2 / 23, kk = 169 + (i2 % 23);
    Vt[d * 192 + (kk ^ ((d & 7) << 3))] = 0;
  }
  __syncthreads();

  for (int qt = w; qt < 11; qt += 4) {
    int q0 = qt * 16;
    int qrow = q0 + lr; if (qrow > 168) qrow = 168;
    bf16x8 qf[4];
    #pragma unroll
    for (int ks = 0; ks < 4; ks++)
      qf[ks] = *(const bf16x8*)(Qp + (long)qrow * 768 + ks * 32 + lg * 8);
    f32x4 sacc[11];
    #pragma unroll
    for (int kt = 0; kt < 11; kt++) {
      sacc[kt] = (f32x4){0.f, 0.f, 0.f, 0.f};
      #pragma unroll
      for (int ks = 0; ks < 4; ks++) {
        int krow = kt * 16 + lr;
        bf16x8 kf = *(const bf16x8*)&Kl[krow * 128 + ((ks * 32 + lg * 8) ^ ((krow & 7) << 3))];
        sacc[kt] = __builtin_amdgcn_mfma_f32_16x16x32_bf16(kf, qf[ks], sacc[kt], 0, 0, 0);
      }
    }
    float sv[11][4];
    float mx = -1e30f;
    #pragma unroll
    for (int kt = 0; kt < 11; kt++)
      #pragma unroll
      for (int i = 0; i < 4; i++) {
        int kk = kt * 16 + lg * 4 + i;
        sv[kt][i] = (kk < 169) ? sacc[kt][i] * scale : -1e30f;
        mx = fmaxf(mx, sv[kt][i]);
      }
    mx = fmaxf(mx, __shfl_xor(mx, 16));
    mx = fmaxf(mx, __shfl_xor(mx, 32));
    float sum = 0.f;
    #pragma unroll
    for (int kt = 0; kt < 11; kt++)
      #pragma unroll
      for (int i = 0; i < 4; i++) {
        float e = (sv[kt][i] > -1e29f) ? expf(sv[kt][i] - mx) : 0.f;
        sv[kt][i] = e; sum += e;
      }
    sum += __shfl_xor(sum, 16);
    sum += __shfl_xor(sum, 32);
    float inv = 1.f / sum;
    #pragma unroll
    for (int kt = 0; kt < 11; kt++)
      #pragma unroll
      for (int i = 0; i < 4; i++) {
        int kk = kt * 16 + lg * 4 + i;
        Pl[w][lr * 192 + (kk ^ ((lr & 7) << 3))] = f2bf(sv[kt][i] * inv);
      }
    if (lg == 0) {
      #pragma unroll
      for (int kk = 176; kk < 192; kk++)
        Pl[w][lr * 192 + (kk ^ ((lr & 7) << 3))] = 0;
    }
    asm volatile("s_waitcnt lgkmcnt(0)" ::: "memory");
    f32x4 oacc[8];
    #pragma unroll
    for (int dt = 0; dt < 8; dt++) oacc[dt] = (f32x4){0.f, 0.f, 0.f, 0.f};
    #pragma unroll
    for (int kt2 = 0; kt2 < 6; kt2++) {
      bf16x8 pf = *(const bf16x8*)&Pl[w][lr * 192 + ((kt2 * 32 + lg * 8) ^ ((lr & 7) << 3))];
      #pragma unroll
      for (int dt = 0; dt < 8; dt++) {
        int dr = dt * 16 + lr;
        bf16x8 vf = *(const bf16x8*)&Vt[dr * 192 + ((kt2 * 32 + lg * 8) ^ ((dr & 7) << 3))];
        oacc[dt] = __builtin_amdgcn_mfma_f32_16x16x32_bf16(pf, vf, oacc[dt], 0, 0, 0);
      }
    }
    #pragma unroll
    for (int dt = 0; dt < 8; dt++)
      #pragma unroll
      for (int i = 0; i < 4; i++) {
        int q = q0 + lg * 4 + i;
        if (q < 169)
          ob[((long)b * 169 + q) * 256 + h * 128 + dt * 16 + lr] = f2bf(oacc[dt][i]);
      }
  }
}

// ---------------------------------------------------------------------------
// elementwise / reduction (unchanged)
// ---------------------------------------------------------------------------
__global__ __launch_bounds__(256) void ln_gelu_512b(
    short* __restrict__ U, const float* __restrict__ g, const float* __restrict__ b, int nrows)
{
  int row = blockIdx.x * 4 + (threadIdx.x >> 6);
  if (row >= nrows) return;
  int l = threadIdx.x & 63;
  short* p = U + (long)row * 512;
  bf16x8 v = *(bf16x8*)(p + l * 8);
  float f[8];
  #pragma unroll
  for (int j = 0; j < 8; j++) f[j] = bf2f(v[j]);
  float s = 0.f;
  #pragma unroll
  for (int j = 0; j < 8; j++) s += f[j];
  float m = wred_sum(s) * (1.f / 512.f);
  float sq = 0.f;
  #pragma unroll
  for (int j = 0; j < 8; j++) { f[j] -= m; sq += f[j] * f[j]; }
  float rstd = rsqrtf(wred_sum(sq) * (1.f / 512.f) + 1e-5f);
  bf16x8 o;
  #pragma unroll
  for (int j = 0; j < 8; j++) o[j] = f2bf(geluf(f[j] * rstd * g[l * 8 + j] + b[l * 8 + j]));
  *(bf16x8*)(p + l * 8) = o;
}

__global__ __launch_bounds__(256) void res_lnb(
    short* __restrict__ y, const short* __restrict__ o,
    const float* __restrict__ g, const float* __restrict__ b)
{
  long row = (long)blockIdx.x * 4 + (threadIdx.x >> 6);
  int l = threadIdx.x & 63;
  short* p = y + row * 256;
  const short* q = o + row * 256;
  s16x4 yv = *(s16x4*)(p + l * 4);
  s16x4 ov = *(const s16x4*)(q + l * 4);
  float t[4];
  #pragma unroll
  for (int j = 0; j < 4; j++) t[j] = bf2f(yv[j]) + bf2f(ov[j]);
  float m = wred_sum(t[0] + t[1] + t[2] + t[3]) * (1.f / 256.f);
  float sq = 0.f;
  #pragma unroll
  for (int j = 0; j < 4; j++) { t[j] -= m; sq += t[j] * t[j]; }
  float rstd = rsqrtf(wred_sum(sq) * (1.f / 256.f) + 1e-5f);
  s16x4 wv;
  #pragma unroll
  for (int j = 0; j < 4; j++) wv[j] = f2bf(t[j] * rstd * g[l * 4 + j] + b[l * 4 + j]);
  *(s16x4*)(p + l * 4) = wv;
}

__global__ __launch_bounds__(256) void final_poolb(
    const short* __restrict__ y, const float* __restrict__ g, const float* __restrict__ b,
    short* __restrict__ hp)
{
  __shared__ float sm[4][256], sx[4][256];
  int bb = blockIdx.x;
  int w = threadIdx.x >> 6, l = threadIdx.x & 63;
  float am[4] = {0.f, 0.f, 0.f, 0.f};
  float ax[4] = {-3.4e38f, -3.4e38f, -3.4e38f, -3.4e38f};
  float gl[4], bl[4];
  #pragma unroll
  for (int j = 0; j < 4; j++) { gl[j] = g[l * 4 + j]; bl[j] = b[l * 4 + j]; }
  for (int s = w; s < 169; s += 4) {
    s16x4 vv = *(const s16x4*)(y + ((long)bb * 169 + s) * 256 + l * 4);
    float t[4];
    #pragma unroll
    for (int j = 0; j < 4; j++) t[j] = bf2f(vv[j]);
    float m = wred_sum(t[0] + t[1] + t[2] + t[3]) * (1.f / 256.f);
    float sq = 0.f;
    #pragma unroll
    for (int j = 0; j < 4; j++) { t[j] -= m; sq += t[j] * t[j]; }
    float rstd = rsqrtf(wred_sum(sq) * (1.f / 256.f) + 1e-5f);
    #pragma unroll
    for (int j = 0; j < 4; j++) {
      float o = t[j] * rstd * gl[j] + bl[j];
      am[j] += o; ax[j] = fmaxf(ax[j], o);
    }
  }
  #pragma unroll
  for (int j = 0; j < 4; j++) { sm[w][l * 4 + j] = am[j]; sx[w][l * 4 + j] = ax[j]; }
  __syncthreads();
  if (w == 0) {
    #pragma unroll
    for (int j = 0; j < 4; j++) {
      int c = l * 4 + j;
      float ms = sm[0][c] + sm[1][c] + sm[2][c] + sm[3][c];
      float mx = fmaxf(fmaxf(sx[0][c], sx[1][c]), fmaxf(sx[2][c], sx[3][c]));
      hp[(long)bb * 512 + c] = f2bf(ms * (1.f / 169.f));
      hp[(long)bb * 512 + 256 + c] = f2bf(mx);
    }
  }
}

// ---------------------------------------------------------------------------
// host
// ---------------------------------------------------------------------------
extern "C" void kernel_launch(void* const* d_in, const int* in_sizes, int n_in,
                              void* d_out, int out_size, void* d_ws, size_t ws_size,
                              hipStream_t stream)
{
  const int*   x        = (const int*)d_in[0];
  const float* emb_tile = (const float*)d_in[1];
  const float* ln_t_g   = (const float*)d_in[2];
  const float* ln_t_b   = (const float*)d_in[3];
  const float* emb_col  = (const float*)d_in[4];
  const float* ln_c_g   = (const float*)d_in[5];
  const float* ln_c_b   = (const float*)d_in[6];
  const float* emb_row  = (const float*)d_in[7];
  const float* ln_r_g   = (const float*)d_in[8];
  const float* ln_r_b   = (const float*)d_in[9];
  const float* efus_W   = (const float*)d_in[10];
  const float* efus_b   = (const float*)d_in[11];
  const float* gru_Wi   = (const float*)d_in[12];
  const float* gru_Wh   = (const float*)d_in[13];
  const float* gru_bi   = (const float*)d_in[14];
  const float* gru_bh   = (const float*)d_in[15];
  const float* rfc1_W   = (const float*)d_in[16];
  const float* rfc1_b   = (const float*)d_in[17];
  const float* rln_g    = (const float*)d_in[18];
  const float* rln_b    = (const float*)d_in[19];
  const float* rfc2_W   = (const float*)d_in[20];
  const float* rfc2_b   = (const float*)d_in[21];
  const float* t_inW    = (const float*)d_in[22];
  const float* t_inb    = (const float*)d_in[23];
  const float* t_outW   = (const float*)d_in[24];
  const float* t_outb   = (const float*)d_in[25];
  const float* t_ln1g   = (const float*)d_in[26];
  const float* t_ln1b   = (const float*)d_in[27];
  const float* t_ff1W   = (const float*)d_in[28];
  const float* t_ff1b   = (const float*)d_in[29];
  const float* t_ff2W   = (const float*)d_in[30];
  const float* t_ff2b   = (const float*)d_in[31];
  const float* t_ln2g   = (const float*)d_in[32];
  const float* t_ln2b   = (const float*)d_in[33];
  const float* fnorm_g  = (const float*)d_in[34];
  const float* fnorm_b  = (const float*)d_in[35];
  const float* ffc_W    = (const float*)d_in[36];
  const float* ffc_b    = (const float*)d_in[37];
  const float* ffc_lng  = (const float*)d_in[38];
  const float* ffc_lnb  = (const float*)d_in[39];
  const float* mu_W     = (const float*)d_in[40];
  const float* mu_b     = (const float*)d_in[41];
  const float* lv_W     = (const float*)d_in[42];
  const float* lv_b     = (const float*)d_in[43];
  float* out = (float*)d_out;

  char* ws = (char*)d_ws;

  // ---- small region ----
  float* te      = (float*)(ws + 0);
  float* ce      = (float*)(ws + 16384);
  float* re      = (float*)(ws + 23040);
  float* tf      = (float*)(ws + 29696);
  float* pf      = (float*)(ws + 62464);
  float* tgi     = (float*)(ws + 235520);
  float* pgi     = (float*)(ws + 432128);
  short* whpk    = (short*)(ws + 1470464);
  short* wp      = (short*)(ws + 3043328);
  short* headsWp = (short*)(ws + 5926912);
  float* headsB  = (float*)(ws + 6057984);
  short* hp      = (short*)(ws + 6058496);
  short* h2      = (short*)(ws + 7107072);

  short* rfc1p = wp;
  short* rfc2p = wp + 262144;
  short* inWp  = wp + 393216;
  short* outWp = wp + 786432;
  short* ff1p  = wp + 917504;
  short* ff2p  = wp + 1048576;
  short* ffcp  = wp + 1179648;

  // ---- big region: hs [173056,512] bf16; Y overlays hs ----
  const size_t o_hs = 8388608;
  short* hs = (short*)(ws + o_hs);
  short* Y  = hs;
  const size_t o_R = o_hs + 177209344ULL;

  // ---- adaptive chunk ----
  size_t Ravail = ws_size > o_R ? ws_size - o_R : 0;
  int NC = 1024;
  while (NC > 32) {
    long Mp_t = (((long)NC * 169 + 127) / 128) * 128;
    if ((size_t)Mp_t * 2560 <= Ravail) break;
    NC >>= 1;
  }
  const long Mp = (((long)NC * 169 + 127) / 128) * 128;
  char* R = ws + o_R;
  // gru exchange buffers overlay R (used only before any R use)
  int* gflags = (int*)R;                           // 256 ints (4 KB slot)
  unsigned long long* ghx = (unsigned long long*)(R + 4096);   // 1 MB
  short* qkvb = (short*)R;
  short* obp  = (short*)(R + Mp * 1536);
  short* o2p  = (short*)(R + Mp * 2048);
  short* Uc   = (short*)R;
  short* ffh  = qkvb;
  short* o2b  = obp;

  // ---- weight conversions + heads pack ----
  WJobs jb;
  jb.s[0] = rfc1_W;  jb.d[0] = rfc1p; jb.n[0] = 262144;
  jb.s[1] = rfc2_W;  jb.d[1] = rfc2p; jb.n[1] = 131072;
  jb.s[2] = t_inW;   jb.d[2] = inWp;  jb.n[2] = 393216;
  jb.s[3] = t_outW;  jb.d[3] = outWp; jb.n[3] = 131072;
  jb.s[4] = t_ff1W;  jb.d[4] = ff1p;  jb.n[4] = 131072;
  jb.s[5] = t_ff2W;  jb.d[5] = ff2p;  jb.n[5] = 131072;
  jb.s[6] = ffc_W;   jb.d[6] = ffcp;  jb.n[6] = 262144;
  wcvt_all<<<dim3(1536, 7), 256, 0, stream>>>(jb);
  prep_heads<<<128, 64, 0, stream>>>(mu_W, lv_W, mu_b, lv_b, headsWp, headsB);

  // ---- precompute ----
  pre_emb<<<58, 64, 0, stream>>>(emb_tile, ln_t_g, ln_t_b, emb_col, ln_c_g, ln_c_b,
                                 emb_row, ln_r_g, ln_r_b, te, ce, re);
  pre_fuse<<<201, 256, 0, stream>>>(te, ce, re, efus_W, efus_b, tf, pf);
  pre_gi<<<201, 256, 0, stream>>>(tf, pf, gru_Wi, gru_bi, tgi, pgi);
  pre_whpack2<<<1536, 64, 0, stream>>>(gru_Wh, whpk);

  // ---- GRU scan (flags + hx reset each call; h0 = 0) ----
  hipMemsetAsync(R, 0, 4096 + 1048576, stream);
  gru_scan4<<<256, 512, 0, stream>>>(x, tgi, pgi, whpk, gru_bh, hs, ghx, gflags);

  const int MT = (int)(Mp / 128);

  // ---- rfc head ----
  for (int cb = 0; cb < 1024; cb += NC) {
    int C = NC * 169;
    const short* hsC = hs + (long)cb * 169 * 512;
    short* Yc = Y + (long)cb * 169 * 256;
    gemm_g<1><<<MT * 4, 256, 0, stream>>>(hsC, 512, rfc1p, 512, rfc1_b, Uc, 512, C, 512, 512, 4);
    ln_gelu_512b<<<C / 4, 256, 0, stream>>>(Uc, rln_g, rln_b, C);
    gemm_g<1><<<MT * 2, 256, 0, stream>>>(Uc, 512, rfc2p, 512, rfc2_b, Yc, 256, C, 256, 512, 2);
  }

  // ---- transformer ----
  for (int cb = 0; cb < 1024; cb += NC) {
    int C = NC * 169;
    short* Yc = Y + (long)cb * 169 * 256;
    for (int i = 0; i < 2; i++) {
      gemm_g<1><<<MT * 6, 256, 0, stream>>>(Yc, 256, inWp + (long)i * 196608, 256,
                                            t_inb + i * 768, qkvb, 768, C, 768, 256, 6);
      attn_fused<<<dim3(NC, 2), 256, 0, stream>>>(qkvb, obp);
      gemm_g<1><<<MT * 2, 256, 0, stream>>>(obp, 256, outWp + i * 65536, 256,
                                            t_outb + i * 256, o2p, 256, C, 256, 256, 2);
      res_lnb<<<C / 4, 256, 0, stream>>>(Yc, o2p, t_ln1g + i * 256, t_ln1b + i * 256);
      gemm_g<2><<<MT * 2, 256, 0, stream>>>(Yc, 256, ff1p + i * 65536, 256,
                                            t_ff1b + i * 256, ffh, 256, C, 256, 256, 2);
      gemm_g<1><<<MT * 2, 256, 0, stream>>>(ffh, 256, ff2p + i * 65536, 256,
                                            t_ff2b + i * 256, o2b, 256, C, 256, 256, 2);
      res_lnb<<<C / 4, 256, 0, stream>>>(Yc, o2b, t_ln2g + i * 256, t_ln2b + i * 256);
    }
  }

  // ---- final norm + pooling + heads ----
  final_poolb<<<1024, 256, 0, stream>>>(Y, fnorm_g, fnorm_b, hp);
  gemm_g<1><<<8 * 4, 256, 0, stream>>>(hp, 512, ffcp, 512, ffc_b, h2, 512, 1024, 512, 512, 4);
  ln_gelu_512b<<<256, 256, 0, stream>>>(h2, ffc_lng, ffc_lnb, 1024);
  gemm_g<3><<<8 * 1, 256, 0, stream>>>(h2, 512, headsWp, 512, headsB, out, 0, 1024, 128, 512, 1);
}